// Round 1
// baseline (441.357 us; speedup 1.0000x reference)
//
#include <hip/hip_runtime.h>
#include <hip/hip_bf16.h>
#include <stdint.h>

#define T_DIM 1024
#define F_DIM 1024
#define H_NUM 16
#define DKD 64
#define DVD 64
#define B_NUM 2

typedef __attribute__((ext_vector_type(8))) short bf16x8;
typedef __attribute__((ext_vector_type(4))) float f32x4;
typedef __attribute__((ext_vector_type(4))) short short4v;

__device__ __forceinline__ short f2b(float f) {
  union { float f; unsigned u; } un; un.f = f;
  unsigned r = un.u + 0x7FFFu + ((un.u >> 16) & 1u);
  return (short)(r >> 16);
}

// ---------------- conversion: f32 -> bf16, n multiple of 4 ----------------
__global__ void cvt_f32_bf16(const float* __restrict__ src, short* __restrict__ dst, int n4) {
  int i = blockIdx.x * blockDim.x + threadIdx.x;
  if (i >= n4) return;
  float4 v = reinterpret_cast<const float4*>(src)[i];
  short4v o;
  o[0] = f2b(v.x); o[1] = f2b(v.y); o[2] = f2b(v.z); o[3] = f2b(v.w);
  reinterpret_cast<short4v*>(dst)[i] = o;
}

// ---------------- bf16 GEMM: C[m,n] = sum_k A[m,k]*Bw[n,k] (+bias) ----------------
// modes: 0 = q (write qu,qv with bq + u/v bias), 1 = k, 2 = v (transposed out),
//        3 = p, 4 = final output (f32)
__global__ __launch_bounds__(256)
void gemm_bt(const short* __restrict__ A, const short* __restrict__ Bw,
             const float* __restrict__ bias, const float* __restrict__ bias2,
             const float* __restrict__ bias3,
             short* __restrict__ out0, short* __restrict__ out1,
             float* __restrict__ outf, int M, int K, int mode)
{
  __shared__ __align__(16) short As[128 * 64];
  __shared__ __align__(16) short Bs[128 * 64];
  const int tid = threadIdx.x;
  const int wave = tid >> 6, lane = tid & 63;
  const int wr = wave >> 1, wc = wave & 1;
  const int tile_m = blockIdx.x * 128, tile_n = blockIdx.y * 128;
  const int lrow = lane >> 3;        // 0..7
  const int lcol = (lane & 7) * 8;   // 0,8,..,56
  const int q15 = lane & 15, q4 = lane >> 4;

  f32x4 acc[4][4];
  for (int i = 0; i < 4; ++i)
    for (int j = 0; j < 4; ++j) acc[i][j] = (f32x4){0.f, 0.f, 0.f, 0.f};

  for (int k0 = 0; k0 < K; k0 += 64) {
    __syncthreads();
    for (int i = 0; i < 4; ++i) {
      int c = wave * 4 + i;
      int row = c * 8 + lrow;
      bf16x8 va = *reinterpret_cast<const bf16x8*>(A + (size_t)(tile_m + row) * K + k0 + lcol);
      *reinterpret_cast<bf16x8*>(&As[row * 64 + lcol]) = va;
      bf16x8 vb = *reinterpret_cast<const bf16x8*>(Bw + (size_t)(tile_n + row) * K + k0 + lcol);
      *reinterpret_cast<bf16x8*>(&Bs[row * 64 + lcol]) = vb;
    }
    __syncthreads();
    for (int kk = 0; kk < 2; ++kk) {
      const int kof = kk * 32 + q4 * 8;
      bf16x8 af[4], bfr[4];
      for (int i = 0; i < 4; ++i)
        af[i] = *reinterpret_cast<const bf16x8*>(&As[(wr * 64 + i * 16 + q15) * 64 + kof]);
      for (int j = 0; j < 4; ++j)
        bfr[j] = *reinterpret_cast<const bf16x8*>(&Bs[(wc * 64 + j * 16 + q15) * 64 + kof]);
      for (int i = 0; i < 4; ++i)
        for (int j = 0; j < 4; ++j)
          acc[i][j] = __builtin_amdgcn_mfma_f32_16x16x32_bf16(af[i], bfr[j], acc[i][j], 0, 0, 0);
    }
  }

  for (int i = 0; i < 4; ++i) {
    for (int j = 0; j < 4; ++j) {
      for (int r = 0; r < 4; ++r) {
        int m = tile_m + wr * 64 + i * 16 + q4 * 4 + r;
        int n = tile_n + wc * 64 + j * 16 + q15;
        float v = acc[i][j][r] + bias[n];
        if (mode == 0) {
          int b = m >> 10, t = m & 1023, h = n >> 6, d = n & 63;
          size_t o = ((size_t)(b * H_NUM + h) * T_DIM + t) * DKD + d;
          out0[o] = f2b(v + bias2[n]);
          out1[o] = f2b(v + bias3[n]);
        } else if (mode == 1) {
          int b = m >> 10, t = m & 1023, h = n >> 6, d = n & 63;
          out0[((size_t)(b * H_NUM + h) * T_DIM + t) * DKD + d] = f2b(v);
        } else if (mode == 2) {
          int b = m >> 10, t = m & 1023, h = n >> 6, d = n & 63;
          out0[((size_t)(b * H_NUM + h) * DVD + d) * T_DIM + t] = f2b(v);
        } else if (mode == 3) {
          int t = m, h = n >> 6, d = n & 63;
          out0[((size_t)h * T_DIM + t) * DKD + d] = f2b(v);
        } else {
          outf[(size_t)m * 1024 + n] = v;
        }
      }
    }
  }
}

// ---------------- fused rel-pos flash attention ----------------
// scores[t,s] = (qu[t].k[s] + qv[t].p[T-1-|t-s|]) / 8 ; softmax over s; O = P.V
__global__ __launch_bounds__(256)
void attn_kernel(const short* __restrict__ qu, const short* __restrict__ qv,
                 const short* __restrict__ kmat, const short* __restrict__ vt,
                 const short* __restrict__ p, short* __restrict__ xout)
{
  __shared__ __align__(16) short Ks[64 * 64];   // [s_loc][dk]
  __shared__ __align__(16) short Vs[64 * 64];   // [dv][s_loc]
  __shared__ __align__(16) float Blds[4][16][128];
  __shared__ __align__(16) short Plds[4][16][64];

  const int tid = threadIdx.x;
  const int wave = tid >> 6, lane = tid & 63;
  const int t0 = blockIdx.x * 64;
  const int h = blockIdx.y;
  const int b = blockIdx.z;
  const int q15 = lane & 15, q4 = lane >> 4;
  const size_t bh = (size_t)(b * H_NUM + h);

  // per-wave q fragments: rows t0 + wave*16 + (0..15)
  bf16x8 quf[2], qvf[2];
  {
    size_t base = (bh * T_DIM + t0 + wave * 16 + q15) * DKD + q4 * 8;
    quf[0] = *reinterpret_cast<const bf16x8*>(qu + base);
    quf[1] = *reinterpret_cast<const bf16x8*>(qu + base + 32);
    qvf[0] = *reinterpret_cast<const bf16x8*>(qv + base);
    qvf[1] = *reinterpret_cast<const bf16x8*>(qv + base + 32);
  }

  f32x4 acco[4];
  for (int g = 0; g < 4; ++g) acco[g] = (f32x4){0.f, 0.f, 0.f, 0.f};
  float mrun[4], lrun[4];
  for (int r = 0; r < 4; ++r) { mrun[r] = -1e30f; lrun[r] = 0.f; }

  for (int s0 = 0; s0 < T_DIM; s0 += 64) {
    __syncthreads();
    for (int pass = 0; pass < 2; ++pass) {
      int flat = pass * 2048 + tid * 8;
      int row = flat >> 6, col = flat & 63;
      *reinterpret_cast<bf16x8*>(&Ks[flat]) =
          *reinterpret_cast<const bf16x8*>(kmat + (bh * T_DIM + s0 + row) * DKD + col);
      *reinterpret_cast<bf16x8*>(&Vs[flat]) =
          *reinterpret_cast<const bf16x8*>(vt + (bh * DVD + row) * T_DIM + s0 + col);
    }
    __syncthreads();

    const int dist0 = (t0 > s0) ? (t0 - s0) : (s0 - t0);
    const int jbase = T_DIM - 64 - dist0;
    const int ngr = (dist0 == 0) ? 4 : 8;

    // AC = qu . K^T  (16x64 per wave)
    f32x4 accac[4];
    for (int g = 0; g < 4; ++g) accac[g] = (f32x4){0.f, 0.f, 0.f, 0.f};
    for (int kc = 0; kc < 2; ++kc) {
      const int kof = kc * 32 + q4 * 8;
      for (int g = 0; g < 4; ++g) {
        bf16x8 kf = *reinterpret_cast<const bf16x8*>(&Ks[(g * 16 + q15) * 64 + kof]);
        accac[g] = __builtin_amdgcn_mfma_f32_16x16x32_bf16(quf[kc], kf, accac[g], 0, 0, 0);
      }
    }
    // Btile = qv . Pwin^T over 128-wide window (B-frags straight from global p)
    f32x4 bacc[8];
    for (int g = 0; g < 8; ++g) bacc[g] = (f32x4){0.f, 0.f, 0.f, 0.f};
    for (int kc = 0; kc < 2; ++kc) {
      const int kof = kc * 32 + q4 * 8;
      for (int g = 0; g < ngr; ++g) {
        int jj = jbase + g * 16 + q15;
        if (jj > T_DIM - 1) jj = T_DIM - 1;
        bf16x8 pf = *reinterpret_cast<const bf16x8*>(p + ((size_t)h * T_DIM + jj) * DKD + kof);
        bacc[g] = __builtin_amdgcn_mfma_f32_16x16x32_bf16(qvf[kc], pf, bacc[g], 0, 0, 0);
      }
    }
    for (int g = 0; g < ngr; ++g)
      for (int r = 0; r < 4; ++r)
        Blds[wave][q4 * 4 + r][g * 16 + q15] = bacc[g][r];

    // scores + online softmax
    float pval[4][4];
    float rmax[4];
    for (int r = 0; r < 4; ++r) rmax[r] = -1e30f;
    for (int g = 0; g < 4; ++g) {
      for (int r = 0; r < 4; ++r) {
        int locR = q4 * 4 + r;
        int tt = t0 + wave * 16 + locR;
        int ss = s0 + g * 16 + q15;
        int d = (tt > ss) ? (tt - ss) : (ss - tt);
        int jp = dist0 + 63 - d;
        float sc = (accac[g][r] + Blds[wave][locR][jp]) * 0.125f;
        pval[g][r] = sc;
        rmax[r] = fmaxf(rmax[r], sc);
      }
    }
    for (int msk = 1; msk < 16; msk <<= 1)
      for (int r = 0; r < 4; ++r) rmax[r] = fmaxf(rmax[r], __shfl_xor(rmax[r], msk));
    float rsum[4], scl[4];
    for (int r = 0; r < 4; ++r) {
      float mn = fmaxf(mrun[r], rmax[r]);
      scl[r] = __expf(mrun[r] - mn);
      mrun[r] = mn;
      float s_ = 0.f;
      for (int g = 0; g < 4; ++g) { pval[g][r] = __expf(pval[g][r] - mn); s_ += pval[g][r]; }
      rsum[r] = s_;
    }
    for (int msk = 1; msk < 16; msk <<= 1)
      for (int r = 0; r < 4; ++r) rsum[r] += __shfl_xor(rsum[r], msk);
    for (int r = 0; r < 4; ++r) lrun[r] = lrun[r] * scl[r] + rsum[r];
    for (int g = 0; g < 4; ++g)
      for (int r = 0; r < 4; ++r) acco[g][r] *= scl[r];

    for (int g = 0; g < 4; ++g)
      for (int r = 0; r < 4; ++r)
        Plds[wave][q4 * 4 + r][g * 16 + q15] = f2b(pval[g][r]);

    // O += P.V
    for (int kc = 0; kc < 2; ++kc) {
      const int kof = kc * 32 + q4 * 8;
      bf16x8 pf = *reinterpret_cast<const bf16x8*>(&Plds[wave][q15][kof]);
      for (int g = 0; g < 4; ++g) {
        bf16x8 vf = *reinterpret_cast<const bf16x8*>(&Vs[(g * 16 + q15) * 64 + kof]);
        acco[g] = __builtin_amdgcn_mfma_f32_16x16x32_bf16(pf, vf, acco[g], 0, 0, 0);
      }
    }
  }

  for (int g = 0; g < 4; ++g)
    for (int r = 0; r < 4; ++r) {
      int tt = t0 + wave * 16 + q4 * 4 + r;
      int dv = g * 16 + q15;
      float o = acco[g][r] / lrun[r];
      xout[((size_t)b * T_DIM + tt) * (H_NUM * DVD) + h * DVD + dv] = f2b(o);
    }
}

// ---------------- launch ----------------
extern "C" void kernel_launch(void* const* d_in, const int* in_sizes, int n_in,
                              void* d_out, int out_size, void* d_ws, size_t ws_size,
                              hipStream_t stream) {
  const float* query = (const float*)d_in[0];
  const float* key   = (const float*)d_in[1];
  const float* value = (const float*)d_in[2];
  const float* pos   = (const float*)d_in[3];
  const float* Wq = (const float*)d_in[4];  const float* bq = (const float*)d_in[5];
  const float* Wk = (const float*)d_in[6];  const float* bk = (const float*)d_in[7];
  const float* Wv = (const float*)d_in[8];  const float* bv = (const float*)d_in[9];
  const float* Wp = (const float*)d_in[10]; const float* bp = (const float*)d_in[11];
  const float* Wo = (const float*)d_in[12]; const float* bo = (const float*)d_in[13];
  const float* ub = (const float*)d_in[14]; const float* vb = (const float*)d_in[15];

  const size_t NBT = (size_t)B_NUM * T_DIM * F_DIM;  // 2097152
  const size_t NTF = (size_t)T_DIM * F_DIM;          // 1048576

  char* ws = (char*)d_ws;
  size_t off = 0;
  auto alloc = [&](size_t elems) { short* q = (short*)(ws + off); off += elems * sizeof(short); return q; };
  short* query_bf = alloc(NBT);
  short* key_bf   = alloc(NBT);
  short* value_bf = alloc(NBT);
  short* pos_bf   = alloc(NTF);
  short* Wq_bf = alloc(NTF);
  short* Wk_bf = alloc(NTF);
  short* Wv_bf = alloc(NTF);
  short* Wp_bf = alloc(NTF);
  short* Wo_bf = alloc(NTF);
  short* qu_bf = alloc(NBT);
  short* qv_bf = alloc(NBT);
  short* k_bf  = alloc(NBT);
  short* vT_bf = alloc(NBT);
  short* p_bf  = alloc(NTF);
  short* x_bf  = alloc(NBT);

  auto cvt = [&](const float* s, short* d, size_t n) {
    int n4 = (int)(n / 4);
    hipLaunchKernelGGL(cvt_f32_bf16, dim3(n4 / 256), dim3(256), 0, stream, s, d, n4);
  };
  cvt(query, query_bf, NBT);
  cvt(key, key_bf, NBT);
  cvt(value, value_bf, NBT);
  cvt(pos, pos_bf, NTF);
  cvt(Wq, Wq_bf, NTF);
  cvt(Wk, Wk_bf, NTF);
  cvt(Wv, Wv_bf, NTF);
  cvt(Wp, Wp_bf, NTF);
  cvt(Wo, Wo_bf, NTF);

  // projections
  hipLaunchKernelGGL(gemm_bt, dim3(16, 8), dim3(256), 0, stream,
                     query_bf, Wq_bf, bq, ub, vb, qu_bf, qv_bf, (float*)nullptr, 2048, 1024, 0);
  hipLaunchKernelGGL(gemm_bt, dim3(16, 8), dim3(256), 0, stream,
                     key_bf, Wk_bf, bk, (const float*)nullptr, (const float*)nullptr,
                     k_bf, (short*)nullptr, (float*)nullptr, 2048, 1024, 1);
  hipLaunchKernelGGL(gemm_bt, dim3(16, 8), dim3(256), 0, stream,
                     value_bf, Wv_bf, bv, (const float*)nullptr, (const float*)nullptr,
                     vT_bf, (short*)nullptr, (float*)nullptr, 2048, 1024, 2);
  hipLaunchKernelGGL(gemm_bt, dim3(8, 8), dim3(256), 0, stream,
                     pos_bf, Wp_bf, bp, (const float*)nullptr, (const float*)nullptr,
                     p_bf, (short*)nullptr, (float*)nullptr, 1024, 1024, 3);

  // attention
  hipLaunchKernelGGL(attn_kernel, dim3(16, 16, 2), dim3(256), 0, stream,
                     qu_bf, qv_bf, k_bf, vT_bf, p_bf, x_bf);

  // output projection (f32 out)
  hipLaunchKernelGGL(gemm_bt, dim3(16, 8), dim3(256), 0, stream,
                     x_bf, Wo_bf, bo, (const float*)nullptr, (const float*)nullptr,
                     (short*)nullptr, (short*)nullptr, (float*)d_out, 2048, 1024, 4);
}

// Round 2
// 152.337 us; speedup vs baseline: 2.8972x; 2.8972x over previous
//
#include <hip/hip_runtime.h>
#include <hip/hip_bf16.h>
#include <stdint.h>

typedef __attribute__((ext_vector_type(8))) short bf16x8;
typedef __attribute__((ext_vector_type(4))) float f32x4;
typedef __attribute__((ext_vector_type(4))) short short4v;

#define SCALE2 0.18033688011112042f  /* (1/8) * log2(e) */

__device__ __forceinline__ short f2b(float f) {
  union { float f; unsigned u; } un; un.f = f;
  unsigned r = un.u + 0x7FFFu + ((un.u >> 16) & 1u);
  return (short)(r >> 16);
}
__device__ __forceinline__ float b2f(short s) {
  union { unsigned u; float f; } un; un.u = ((unsigned)(unsigned short)s) << 16;
  return un.f;
}

// async global->LDS, 16B per lane; LDS dest is wave-uniform base + lane*16
#define GLDS(GP, LP) __builtin_amdgcn_global_load_lds( \
    (__attribute__((address_space(1))) void*)(GP), \
    (__attribute__((address_space(3))) void*)(LP), 16, 0, 0)

// ---------------- fused f32 -> bf16 conversion (12 chunks of 256K float4) ----------------
struct CvtTab { const float* s[12]; short* d[12]; };

__global__ void cvt_all(CvtTab tab) {
  int chunk = blockIdx.x >> 10;                       // 1024 blocks per chunk
  int off = (blockIdx.x & 1023) * 256 + threadIdx.x;  // float4 index in chunk
  float4 v = *((const float4*)tab.s[chunk] + off);
  short4v o;
  o[0] = f2b(v.x); o[1] = f2b(v.y); o[2] = f2b(v.z); o[3] = f2b(v.w);
  *((short4v*)tab.d[chunk] + off) = o;
}

// ---------------- 128x128 bf16 GEMM core, K=1024, gload_lds + XOR swizzle ----------------
__device__ __forceinline__ void gemm_core128(
    const short* __restrict__ A, const short* __restrict__ W,
    int tile_m, int tile_n, short* As, short* Bs, f32x4 acc[4][4])
{
  const int tid = threadIdx.x;
  const int wave = tid >> 6, lane = tid & 63;
  const int wr = wave >> 1, wc = wave & 1;
  const int q15 = lane & 15, q4 = lane >> 4;
  const int rl = lane >> 3;
  const int cswz = ((lane & 7) * 16) ^ (rl << 4);     // pre-swizzled source col (bytes)

#pragma unroll
  for (int i = 0; i < 4; ++i)
#pragma unroll
    for (int j = 0; j < 4; ++j) acc[i][j] = (f32x4){0.f, 0.f, 0.f, 0.f};

  for (int k0 = 0; k0 < 1024; k0 += 64) {
    __syncthreads();
#pragma unroll
    for (int s = 0; s < 4; ++s) {
      int ia = wave * 4 + s;            // 0..15, covers 8 rows (128B each) per inst
      int row = ia * 8 + rl;
      GLDS(A + (size_t)(tile_m + row) * 1024 + k0 + (cswz >> 1), (char*)As + ia * 1024);
      GLDS(W + (size_t)(tile_n + row) * 1024 + k0 + (cswz >> 1), (char*)Bs + ia * 1024);
    }
    __syncthreads();
#pragma unroll
    for (int kk = 0; kk < 2; ++kk) {
      const int kbyte = kk * 64 + q4 * 16;
      const int rswz = (q15 & 7) << 4;
      bf16x8 af[4], bfr[4];
#pragma unroll
      for (int i = 0; i < 4; ++i)
        af[i] = *(const bf16x8*)((const char*)As + (wr * 64 + i * 16 + q15) * 128 + (kbyte ^ rswz));
#pragma unroll
      for (int j = 0; j < 4; ++j)
        bfr[j] = *(const bf16x8*)((const char*)Bs + (wc * 64 + j * 16 + q15) * 128 + (kbyte ^ rswz));
#pragma unroll
      for (int i = 0; i < 4; ++i)
#pragma unroll
        for (int j = 0; j < 4; ++j)
          acc[i][j] = __builtin_amdgcn_mfma_f32_16x16x32_bf16(af[i], bfr[j], acc[i][j], 0, 0, 0);
    }
  }
}

// ---------------- stacked QKVP projection GEMM ----------------
__global__ __launch_bounds__(256)
void gemm_qkvp(const short* __restrict__ q_in, const short* __restrict__ k_in,
               const short* __restrict__ v_in, const short* __restrict__ p_in,
               const short* __restrict__ wq, const short* __restrict__ wk,
               const short* __restrict__ wv, const short* __restrict__ wp,
               const float* __restrict__ bq, const float* __restrict__ bk,
               const float* __restrict__ bv, const float* __restrict__ bp,
               const float* __restrict__ ub, const float* __restrict__ vb,
               short* __restrict__ qu, short* __restrict__ qv,
               short* __restrict__ kx, short* __restrict__ vtp, short* __restrict__ pp)
{
  __shared__ __align__(16) short As[128 * 64];
  __shared__ __align__(16) short Bs[128 * 64];
  const int bx = blockIdx.x;
  const short* A; const short* W; const float* bias; int tm, mode;
  if (bx < 16)      { A = q_in; W = wq; bias = bq; tm = bx;      mode = 0; }
  else if (bx < 32) { A = k_in; W = wk; bias = bk; tm = bx - 16; mode = 1; }
  else if (bx < 48) { A = v_in; W = wv; bias = bv; tm = bx - 32; mode = 2; }
  else              { A = p_in; W = wp; bias = bp; tm = bx - 48; mode = 3; }

  f32x4 acc[4][4];
  gemm_core128(A, W, tm * 128, blockIdx.y * 128, As, Bs, acc);

  const int lane = threadIdx.x & 63, wave = threadIdx.x >> 6;
  const int wr = wave >> 1, wc = wave & 1, q15 = lane & 15, q4 = lane >> 4;
#pragma unroll
  for (int i = 0; i < 4; ++i)
#pragma unroll
    for (int j = 0; j < 4; ++j)
#pragma unroll
      for (int r = 0; r < 4; ++r) {
        int m = tm * 128 + wr * 64 + i * 16 + q4 * 4 + r;
        int n = blockIdx.y * 128 + wc * 64 + j * 16 + q15;
        float v = acc[i][j][r] + bias[n];
        int bb = m >> 10, t = m & 1023, hh = n >> 6, d = n & 63;
        if (mode == 0) {
          size_t o = ((size_t)(bb * 16 + hh) * 1024 + t) * 64 + d;
          qu[o] = f2b(v + ub[n]);
          qv[o] = f2b(v + vb[n]);
        } else if (mode == 1) {
          kx[((size_t)(bb * 16 + hh) * 1024 + t) * 64 + d] = f2b(v);
        } else if (mode == 2) {
          vtp[((size_t)(bb * 16 + hh) * 64 + d) * 1024 + t] = f2b(v);
        } else {
          pp[((size_t)hh * 1024 + m) * 64 + d] = f2b(v);
        }
      }
}

// ---------------- output GEMM (f32 out) ----------------
__global__ __launch_bounds__(256)
void gemm_out(const short* __restrict__ X, const short* __restrict__ W,
              const float* __restrict__ bo, float* __restrict__ out)
{
  __shared__ __align__(16) short As[128 * 64];
  __shared__ __align__(16) short Bs[128 * 64];
  f32x4 acc[4][4];
  gemm_core128(X, W, blockIdx.x * 128, blockIdx.y * 128, As, Bs, acc);
  const int lane = threadIdx.x & 63, wave = threadIdx.x >> 6;
  const int wr = wave >> 1, wc = wave & 1, q15 = lane & 15, q4 = lane >> 4;
#pragma unroll
  for (int i = 0; i < 4; ++i)
#pragma unroll
    for (int j = 0; j < 4; ++j)
#pragma unroll
      for (int r = 0; r < 4; ++r) {
        int m = blockIdx.x * 128 + wr * 64 + i * 16 + q4 * 4 + r;
        int n = blockIdx.y * 128 + wc * 64 + j * 16 + q15;
        out[(size_t)m * 1024 + n] = acc[i][j][r] + bo[n];
      }
}

// ---------------- fused rel-pos flash attention, split-s x2 ----------------
// scores2[t,s] = (qu[t].k[s] + qv[t].p[1023-|t-s|]) * SCALE2 (log2 domain)
#define COMPUTE_BD(GLO) do { \
  _Pragma("unroll") \
  for (int g_ = 0; g_ < 4; ++g_) bacc[(GLO) + g_] = (f32x4){0.f, 0.f, 0.f, 0.f}; \
  _Pragma("unroll") \
  for (int kc_ = 0; kc_ < 2; ++kc_) { \
    const int kof_ = kc_ * 32 + q4 * 8; \
    _Pragma("unroll") \
    for (int g_ = 0; g_ < 4; ++g_) { \
      const int jj_ = jbase + ((GLO) + g_) * 16 + q15; \
      bf16x8 pf_ = *(const bf16x8*)(pW + (size_t)jj_ * 64 + kof_); \
      bacc[(GLO) + g_] = __builtin_amdgcn_mfma_f32_16x16x32_bf16(qvf[kc_], pf_, bacc[(GLO) + g_], 0, 0, 0); \
    } \
  } \
} while (0)

__global__ __launch_bounds__(256)
void attn_kernel(const short* __restrict__ qu, const short* __restrict__ qv,
                 const short* __restrict__ kmat, const short* __restrict__ vt,
                 const short* __restrict__ p,
                 float* __restrict__ Opart, float* __restrict__ marr,
                 float* __restrict__ larr)
{
  __shared__ __align__(16) short Ks[64 * 64];  // [s_loc][dk], swizzled
  __shared__ __align__(16) short Vs[64 * 64];  // [dv][s_loc], swizzled
  __shared__ __align__(16) short Bl[4 * 2048]; // per-wave 16 x 128 bf16, swizzled
  __shared__ __align__(16) short Pl[4 * 1024]; // per-wave 16 x 64 bf16, swizzled

  const int tid = threadIdx.x;
  const int wave = tid >> 6, lane = tid & 63;
  const int t0 = blockIdx.x * 64;
  const int h = blockIdx.y;
  const int b = blockIdx.z >> 1;
  const int sh = blockIdx.z & 1;
  const int q15 = lane & 15, q4 = lane >> 4;
  const size_t bh = (size_t)(b * 16 + h);
  const short* pW = p + (size_t)h * 1024 * 64;
  const int rl = lane >> 3;
  const int cswz = ((lane & 7) * 16) ^ (rl << 4);
  const int rswz = (q15 & 7) << 4;
  const int swB = q4 << 5;
  char* BlW = (char*)Bl + wave * 4096;
  char* PlW = (char*)Pl + wave * 2048;

  bf16x8 quf[2], qvf[2];
  {
    size_t base = (bh * 1024 + t0 + wave * 16 + q15) * 64 + q4 * 8;
    quf[0] = *(const bf16x8*)(qu + base);
    quf[1] = *(const bf16x8*)(qu + base + 32);
    qvf[0] = *(const bf16x8*)(qv + base);
    qvf[1] = *(const bf16x8*)(qv + base + 32);
  }

  f32x4 acco[4], bacc[8];
#pragma unroll
  for (int g = 0; g < 4; ++g) acco[g] = (f32x4){0.f, 0.f, 0.f, 0.f};
#pragma unroll
  for (int g = 0; g < 8; ++g) bacc[g] = (f32x4){0.f, 0.f, 0.f, 0.f};
  float mrun[4], lrun[4];
#pragma unroll
  for (int r = 0; r < 4; ++r) { mrun[r] = -1e30f; lrun[r] = 0.f; }

  const int sbeg = sh * 512;
  bool first = true;
  for (int s0 = sbeg; s0 < sbeg + 512; s0 += 64) {
    __syncthreads();
    // stage K (waves 0-1) and V (waves 2-3): linear LDS dest, pre-swizzled source
#pragma unroll
    for (int s = 0; s < 4; ++s) {
      int idx = wave * 4 + s;
      if (idx < 8) {
        int row = idx * 8 + rl;
        GLDS(kmat + (bh * 1024 + s0 + row) * 64 + (cswz >> 1), (char*)Ks + idx * 1024);
      } else {
        int i2 = idx - 8;
        int row = i2 * 8 + rl;
        GLDS(vt + ((bh * 64 + row) * 1024 + s0) + (cswz >> 1), (char*)Vs + i2 * 1024);
      }
    }
    __syncthreads();

    const int dist0 = (t0 > s0) ? (t0 - s0) : (s0 - t0);
    const int jbase = 960 - dist0;

    // AC = qu . K^T
    f32x4 accac[4];
#pragma unroll
    for (int g = 0; g < 4; ++g) accac[g] = (f32x4){0.f, 0.f, 0.f, 0.f};
#pragma unroll
    for (int kc = 0; kc < 2; ++kc) {
      const int kbyte = kc * 64 + q4 * 16;
#pragma unroll
      for (int g = 0; g < 4; ++g) {
        bf16x8 kf = *(const bf16x8*)((const char*)Ks + (g * 16 + q15) * 128 + (kbyte ^ rswz));
        accac[g] = __builtin_amdgcn_mfma_f32_16x16x32_bf16(quf[kc], kf, accac[g], 0, 0, 0);
      }
    }

    // BD rolling window: reuse overlapping 64 rows, compute only 4 new groups
    if (first) {
      COMPUTE_BD(0);
      if (dist0 > 0) COMPUTE_BD(4);
    } else if (s0 <= t0) {
      bacc[0] = bacc[4]; bacc[1] = bacc[5]; bacc[2] = bacc[6]; bacc[3] = bacc[7];
      if (dist0 > 0) COMPUTE_BD(4);
    } else {
      bacc[7] = bacc[3]; bacc[6] = bacc[2]; bacc[5] = bacc[1]; bacc[4] = bacc[0];
      COMPUTE_BD(0);
    }
    first = false;

    // write B window to LDS (bf16, swizzled)
#pragma unroll
    for (int g = 0; g < 8; ++g)
#pragma unroll
      for (int r = 0; r < 4; ++r) {
        int locR = q4 * 4 + r;
        *(short*)(BlW + locR * 256 + (((g * 16 + q15) * 2) ^ swB)) = f2b(bacc[g][r]);
      }

    // scores + online softmax (log2 domain)
    float pv[4][4], rmax[4];
#pragma unroll
    for (int r = 0; r < 4; ++r) rmax[r] = -1e30f;
#pragma unroll
    for (int g = 0; g < 4; ++g)
#pragma unroll
      for (int r = 0; r < 4; ++r) {
        int locR = q4 * 4 + r;
        int tt = t0 + wave * 16 + locR;
        int ss = s0 + g * 16 + q15;
        int d = (tt > ss) ? tt - ss : ss - tt;
        int jp = dist0 + 63 - d;
        float bd = b2f(*(const short*)(BlW + locR * 256 + ((jp * 2) ^ swB)));
        float sc = (accac[g][r] + bd) * SCALE2;
        pv[g][r] = sc;
        rmax[r] = fmaxf(rmax[r], sc);
      }
#pragma unroll
    for (int m = 1; m < 16; m <<= 1)
#pragma unroll
      for (int r = 0; r < 4; ++r) rmax[r] = fmaxf(rmax[r], __shfl_xor(rmax[r], m));
    float scl[4], rsum[4];
#pragma unroll
    for (int r = 0; r < 4; ++r) {
      float mn = fmaxf(mrun[r], rmax[r]);
      scl[r] = exp2f(mrun[r] - mn);
      mrun[r] = mn;
      float s_ = 0.f;
#pragma unroll
      for (int g = 0; g < 4; ++g) { pv[g][r] = exp2f(pv[g][r] - mn); s_ += pv[g][r]; }
      rsum[r] = s_;
    }
#pragma unroll
    for (int m = 1; m < 16; m <<= 1)
#pragma unroll
      for (int r = 0; r < 4; ++r) rsum[r] += __shfl_xor(rsum[r], m);
#pragma unroll
    for (int r = 0; r < 4; ++r) lrun[r] = lrun[r] * scl[r] + rsum[r];
#pragma unroll
    for (int g = 0; g < 4; ++g)
#pragma unroll
      for (int r = 0; r < 4; ++r) acco[g][r] *= scl[r];

    // P -> LDS (bf16, swizzled)
#pragma unroll
    for (int g = 0; g < 4; ++g)
#pragma unroll
      for (int r = 0; r < 4; ++r) {
        int locR = q4 * 4 + r;
        *(short*)(PlW + locR * 128 + (((g * 16 + q15) * 2) ^ ((locR & 7) << 4))) = f2b(pv[g][r]);
      }

    // O += P.V
#pragma unroll
    for (int kc = 0; kc < 2; ++kc) {
      const int kbyte = kc * 64 + q4 * 16;
      bf16x8 pf = *(const bf16x8*)((const char*)PlW + q15 * 128 + (kbyte ^ rswz));
#pragma unroll
      for (int g = 0; g < 4; ++g) {
        bf16x8 vf = *(const bf16x8*)((const char*)Vs + (g * 16 + q15) * 128 + (kbyte ^ rswz));
        acco[g] = __builtin_amdgcn_mfma_f32_16x16x32_bf16(pf, vf, acco[g], 0, 0, 0);
      }
    }
  }

  // partial outputs (unnormalized O, running m/l)
  size_t obase = ((size_t)(sh * 2 + b) * 16 + h) * 1024;
#pragma unroll
  for (int g = 0; g < 4; ++g)
#pragma unroll
    for (int r = 0; r < 4; ++r) {
      int tt = t0 + wave * 16 + q4 * 4 + r;
      Opart[(obase + tt) * 64 + g * 16 + q15] = acco[g][r];
    }
  if (q15 == 0)
#pragma unroll
    for (int r = 0; r < 4; ++r) {
      int tt = t0 + wave * 16 + q4 * 4 + r;
      marr[obase + tt] = mrun[r];
      larr[obase + tt] = lrun[r];
    }
}

// ---------------- combine split-s halves ----------------
__global__ void combine_k(const float* __restrict__ O, const float* __restrict__ marr,
                          const float* __restrict__ larr, short* __restrict__ x)
{
  int i = blockIdx.x * 256 + threadIdx.x;  // 512K threads, 4 dv each
  int dv4 = i & 15, rest = i >> 4;         // rest = (b*16+h)*1024 + t
  float4 a0 = *(const float4*)(O + (size_t)rest * 64 + dv4 * 4);
  float4 a1 = *(const float4*)(O + 2097152 + (size_t)rest * 64 + dv4 * 4);
  float m0 = marr[rest], m1 = marr[32768 + rest];
  float l0 = larr[rest], l1 = larr[32768 + rest];
  float mm = fmaxf(m0, m1);
  float w0 = exp2f(m0 - mm), w1 = exp2f(m1 - mm);
  float inv = 1.0f / (l0 * w0 + l1 * w1);
  int bq = rest >> 14, hq = (rest >> 10) & 15, tq = rest & 1023;
  short4v o;
  o[0] = f2b((a0.x * w0 + a1.x * w1) * inv);
  o[1] = f2b((a0.y * w0 + a1.y * w1) * inv);
  o[2] = f2b((a0.z * w0 + a1.z * w1) * inv);
  o[3] = f2b((a0.w * w0 + a1.w * w1) * inv);
  *(short4v*)(x + ((size_t)(bq * 1024 + tq) * 1024 + hq * 64 + dv4 * 4)) = o;
}

// ---------------- launch ----------------
extern "C" void kernel_launch(void* const* d_in, const int* in_sizes, int n_in,
                              void* d_out, int out_size, void* d_ws, size_t ws_size,
                              hipStream_t stream) {
  const float* query = (const float*)d_in[0];
  const float* key   = (const float*)d_in[1];
  const float* value = (const float*)d_in[2];
  const float* pos   = (const float*)d_in[3];
  const float* Wq = (const float*)d_in[4];  const float* bq = (const float*)d_in[5];
  const float* Wk = (const float*)d_in[6];  const float* bk = (const float*)d_in[7];
  const float* Wv = (const float*)d_in[8];  const float* bv = (const float*)d_in[9];
  const float* Wp = (const float*)d_in[10]; const float* bp = (const float*)d_in[11];
  const float* Wo = (const float*)d_in[12]; const float* bo = (const float*)d_in[13];
  const float* ub = (const float*)d_in[14]; const float* vb = (const float*)d_in[15];

  char* ws = (char*)d_ws;
  const size_t MB = 1 << 20;
  short* Wo_bf    = (short*)(ws);            // 2MB
  short* qu_bf    = (short*)(ws + 2 * MB);   // 4MB
  short* qv_bf    = (short*)(ws + 6 * MB);   // 4MB
  short* k_bf     = (short*)(ws + 10 * MB);  // 4MB
  short* vT_bf    = (short*)(ws + 14 * MB);  // 4MB
  short* p_bf     = (short*)(ws + 18 * MB);  // 2MB
  short* x_bf     = (short*)(ws + 20 * MB);  // 4MB
  short* query_bf = (short*)(ws + 24 * MB);  // 4MB  (dead after gemm_qkvp)
  short* key_bf   = (short*)(ws + 28 * MB);  // 4MB
  short* value_bf = (short*)(ws + 32 * MB);  // 4MB
  short* pos_bf   = (short*)(ws + 36 * MB);  // 2MB
  short* Wq_bf    = (short*)(ws + 38 * MB);  // 2MB
  short* Wk_bf    = (short*)(ws + 40 * MB);  // 2MB
  short* Wv_bf    = (short*)(ws + 42 * MB);  // 2MB
  short* Wp_bf    = (short*)(ws + 44 * MB);  // 2MB -> 46MB total
  // aliases (valid: written after their underlying buffers are dead)
  float* Opart = (float*)(ws + 24 * MB);     // 16MB over query/key/value/pos
  float* marr  = (float*)(ws + 40 * MB);     // 256KB over Wk_bf
  float* larr  = (float*)(ws + 40 * MB + 256 * 1024);

  CvtTab tab;
  tab.s[0] = query;           tab.d[0] = query_bf;
  tab.s[1] = query + 1048576; tab.d[1] = query_bf + 1048576;
  tab.s[2] = key;             tab.d[2] = key_bf;
  tab.s[3] = key + 1048576;   tab.d[3] = key_bf + 1048576;
  tab.s[4] = value;           tab.d[4] = value_bf;
  tab.s[5] = value + 1048576; tab.d[5] = value_bf + 1048576;
  tab.s[6] = pos;             tab.d[6] = pos_bf;
  tab.s[7] = Wq;              tab.d[7] = Wq_bf;
  tab.s[8] = Wk;              tab.d[8] = Wk_bf;
  tab.s[9] = Wv;              tab.d[9] = Wv_bf;
  tab.s[10] = Wp;             tab.d[10] = Wp_bf;
  tab.s[11] = Wo;             tab.d[11] = Wo_bf;
  hipLaunchKernelGGL(cvt_all, dim3(12288), dim3(256), 0, stream, tab);

  hipLaunchKernelGGL(gemm_qkvp, dim3(56, 8), dim3(256), 0, stream,
                     query_bf, key_bf, value_bf, pos_bf,
                     Wq_bf, Wk_bf, Wv_bf, Wp_bf,
                     bq, bk, bv, bp, ub, vb,
                     qu_bf, qv_bf, k_bf, vT_bf, p_bf);

  hipLaunchKernelGGL(attn_kernel, dim3(16, 16, 4), dim3(256), 0, stream,
                     qu_bf, qv_bf, k_bf, vT_bf, p_bf, Opart, marr, larr);

  hipLaunchKernelGGL(combine_k, dim3(2048), dim3(256), 0, stream,
                     Opart, marr, larr, x_bf);

  hipLaunchKernelGGL(gemm_out, dim3(16, 8), dim3(256), 0, stream,
                     x_bf, Wo_bf, bo, (float*)d_out);
}

// Round 3
// 137.927 us; speedup vs baseline: 3.1999x; 1.1045x over previous
//
#include <hip/hip_runtime.h>
#include <hip/hip_bf16.h>
#include <stdint.h>

typedef __attribute__((ext_vector_type(8))) short bf16x8;
typedef __attribute__((ext_vector_type(4))) float f32x4;
typedef __attribute__((ext_vector_type(4))) short short4v;

#define SCALE2 0.18033688011112042f  /* (1/8) * log2(e) */

__device__ __forceinline__ short f2b(float f) {
  union { float f; unsigned u; } un; un.f = f;
  unsigned r = un.u + 0x7FFFu + ((un.u >> 16) & 1u);
  return (short)(r >> 16);
}
__device__ __forceinline__ float b2f(short s) {
  union { unsigned u; float f; } un; un.u = ((unsigned)(unsigned short)s) << 16;
  return un.f;
}

// async global->LDS, 16B per lane; LDS dest is wave-uniform base + lane*16
#define GLDS(GP, LP) __builtin_amdgcn_global_load_lds( \
    (__attribute__((address_space(1))) void*)(GP), \
    (__attribute__((address_space(3))) void*)(LP), 16, 0, 0)

// ---------------- fused f32 -> bf16 conversion ----------------
struct CvtTab { const float* s[12]; short* d[12]; };

__global__ void cvt_all(CvtTab tab) {
  int chunk = blockIdx.x >> 10;
  int off = (blockIdx.x & 1023) * 256 + threadIdx.x;
  float4 v = *((const float4*)tab.s[chunk] + off);
  short4v o;
  o[0] = f2b(v.x); o[1] = f2b(v.y); o[2] = f2b(v.z); o[3] = f2b(v.w);
  *((short4v*)tab.d[chunk] + off) = o;
}

// ---------------- 128x128 bf16 GEMM core, K=1024, 2-phase dbuf ----------------
__device__ __forceinline__ void gemm_core128(
    const short* __restrict__ A, const short* __restrict__ W,
    int tile_m, int tile_n, short* lds, f32x4 acc[4][4])
{
  const int tid = threadIdx.x;
  const int wave = tid >> 6, lane = tid & 63;
  const int wr = wave >> 1, wc = wave & 1;
  const int q15 = lane & 15, q4 = lane >> 4;
  const int rl = lane >> 3;
  const int cswz = ((lane & 7) * 16) ^ (rl << 4);

#pragma unroll
  for (int i = 0; i < 4; ++i)
#pragma unroll
    for (int j = 0; j < 4; ++j) acc[i][j] = (f32x4){0.f, 0.f, 0.f, 0.f};

  auto stage = [&](int buf, int k0) {
    short* As = lds + buf * 16384;
    short* Bs = As + 8192;
#pragma unroll
    for (int s = 0; s < 4; ++s) {
      int ia = wave * 4 + s;
      int row = ia * 8 + rl;
      GLDS(A + (size_t)(tile_m + row) * 1024 + k0 + (cswz >> 1), (char*)As + ia * 1024);
      GLDS(W + (size_t)(tile_n + row) * 1024 + k0 + (cswz >> 1), (char*)Bs + ia * 1024);
    }
  };

  stage(0, 0);
  __syncthreads();
  for (int t = 0; t < 16; ++t) {
    const int cur = t & 1;
    if (t < 15) stage(cur ^ 1, (t + 1) * 64);
    const short* As = lds + cur * 16384;
    const short* Bs = As + 8192;
#pragma unroll
    for (int kk = 0; kk < 2; ++kk) {
      const int kbyte = kk * 64 + q4 * 16;
      const int rswz = (q15 & 7) << 4;
      bf16x8 af[4], bfr[4];
#pragma unroll
      for (int i = 0; i < 4; ++i)
        af[i] = *(const bf16x8*)((const char*)As + (wr * 64 + i * 16 + q15) * 128 + (kbyte ^ rswz));
#pragma unroll
      for (int j = 0; j < 4; ++j)
        bfr[j] = *(const bf16x8*)((const char*)Bs + (wc * 64 + j * 16 + q15) * 128 + (kbyte ^ rswz));
#pragma unroll
      for (int i = 0; i < 4; ++i)
#pragma unroll
        for (int j = 0; j < 4; ++j)
          acc[i][j] = __builtin_amdgcn_mfma_f32_16x16x32_bf16(af[i], bfr[j], acc[i][j], 0, 0, 0);
    }
    __syncthreads();
  }
}

// ---------------- stacked QKVP projection GEMM ----------------
__global__ __launch_bounds__(256)
void gemm_qkvp(const short* __restrict__ q_in, const short* __restrict__ k_in,
               const short* __restrict__ v_in, const short* __restrict__ p_in,
               const short* __restrict__ wq, const short* __restrict__ wk,
               const short* __restrict__ wv, const short* __restrict__ wp,
               const float* __restrict__ bq, const float* __restrict__ bk,
               const float* __restrict__ bv, const float* __restrict__ bp,
               const float* __restrict__ ub, const float* __restrict__ vb,
               short* __restrict__ qu, short* __restrict__ qv,
               short* __restrict__ kx, short* __restrict__ vtp, short* __restrict__ pp)
{
  __shared__ __align__(16) short lds[32768];
  // XCD swizzle: n%8 = weight-panel index -> one XCD per n-panel
  const int n = blockIdx.x;
  const int by = n & 7;       // n-tile
  const int bx = n >> 3;      // stacked m-tile 0..55
  const short* A; const short* W; const float* bias; int tm, mode;
  if (bx < 16)      { A = q_in; W = wq; bias = bq; tm = bx;      mode = 0; }
  else if (bx < 32) { A = k_in; W = wk; bias = bk; tm = bx - 16; mode = 1; }
  else if (bx < 48) { A = v_in; W = wv; bias = bv; tm = bx - 32; mode = 2; }
  else              { A = p_in; W = wp; bias = bp; tm = bx - 48; mode = 3; }

  f32x4 acc[4][4];
  gemm_core128(A, W, tm * 128, by * 128, lds, acc);

  const int lane = threadIdx.x & 63, wave = threadIdx.x >> 6;
  const int wr = wave >> 1, wc = wave & 1, q15 = lane & 15, q4 = lane >> 4;
#pragma unroll
  for (int i = 0; i < 4; ++i)
#pragma unroll
    for (int j = 0; j < 4; ++j)
#pragma unroll
      for (int r = 0; r < 4; ++r) {
        int m = tm * 128 + wr * 64 + i * 16 + q4 * 4 + r;
        int nn = by * 128 + wc * 64 + j * 16 + q15;
        float v = acc[i][j][r] + bias[nn];
        int bb = m >> 10, t = m & 1023, hh = nn >> 6, d = nn & 63;
        if (mode == 0) {
          size_t o = ((size_t)(bb * 16 + hh) * 1024 + t) * 64 + d;
          qu[o] = f2b(v + ub[nn]);
          qv[o] = f2b(v + vb[nn]);
        } else if (mode == 1) {
          kx[((size_t)(bb * 16 + hh) * 1024 + t) * 64 + d] = f2b(v);
        } else if (mode == 2) {
          vtp[((size_t)(bb * 16 + hh) * 64 + d) * 1024 + t] = f2b(v);
        } else {
          pp[((size_t)hh * 1024 + m) * 64 + d] = f2b(v);
        }
      }
}

// ---------------- output GEMM, 128x64 tiles (256 blocks), f32 out ----------------
__global__ __launch_bounds__(256)
void gemm_out(const short* __restrict__ X, const short* __restrict__ W,
              const float* __restrict__ bo, float* __restrict__ out)
{
  __shared__ __align__(16) short lds[24576];  // (128x64 A + 64x64 B) x 2 buf
  const int n = blockIdx.x;
  const int bxm = (n >> 3) & 15;
  const int byn = ((n & 7) << 1) | (n >> 7);
  const int tile_m = bxm * 128, tile_n = byn * 64;

  const int tid = threadIdx.x;
  const int wave = tid >> 6, lane = tid & 63;
  const int wr = wave >> 1, wc = wave & 1;
  const int q15 = lane & 15, q4 = lane >> 4;
  const int rl = lane >> 3;
  const int cswz = ((lane & 7) * 16) ^ (rl << 4);

  f32x4 acc[4][2];
#pragma unroll
  for (int i = 0; i < 4; ++i)
#pragma unroll
    for (int j = 0; j < 2; ++j) acc[i][j] = (f32x4){0.f, 0.f, 0.f, 0.f};

  auto stage = [&](int buf, int k0) {
    short* As = lds + buf * 12288;
    short* Bs = As + 8192;
#pragma unroll
    for (int s = 0; s < 6; ++s) {
      int idx = wave * 6 + s;
      if (idx < 16) {
        int row = idx * 8 + rl;
        GLDS(X + (size_t)(tile_m + row) * 1024 + k0 + (cswz >> 1), (char*)As + idx * 1024);
      } else {
        int i2 = idx - 16;
        int row = i2 * 8 + rl;
        GLDS(W + (size_t)(tile_n + row) * 1024 + k0 + (cswz >> 1), (char*)Bs + i2 * 1024);
      }
    }
  };

  stage(0, 0);
  __syncthreads();
  for (int t = 0; t < 16; ++t) {
    const int cur = t & 1;
    if (t < 15) stage(cur ^ 1, (t + 1) * 64);
    const short* As = lds + cur * 12288;
    const short* Bs = As + 8192;
#pragma unroll
    for (int kk = 0; kk < 2; ++kk) {
      const int kbyte = kk * 64 + q4 * 16;
      const int rswz = (q15 & 7) << 4;
      bf16x8 af[4], bfr[2];
#pragma unroll
      for (int i = 0; i < 4; ++i)
        af[i] = *(const bf16x8*)((const char*)As + (wr * 64 + i * 16 + q15) * 128 + (kbyte ^ rswz));
#pragma unroll
      for (int j = 0; j < 2; ++j)
        bfr[j] = *(const bf16x8*)((const char*)Bs + (wc * 32 + j * 16 + q15) * 128 + (kbyte ^ rswz));
#pragma unroll
      for (int i = 0; i < 4; ++i)
#pragma unroll
        for (int j = 0; j < 2; ++j)
          acc[i][j] = __builtin_amdgcn_mfma_f32_16x16x32_bf16(af[i], bfr[j], acc[i][j], 0, 0, 0);
    }
    __syncthreads();
  }

#pragma unroll
  for (int i = 0; i < 4; ++i)
#pragma unroll
    for (int j = 0; j < 2; ++j)
#pragma unroll
      for (int r = 0; r < 4; ++r) {
        int m = tile_m + wr * 64 + i * 16 + q4 * 4 + r;
        int nn = tile_n + wc * 32 + j * 16 + q15;
        out[(size_t)m * 1024 + nn] = acc[i][j][r] + bo[nn];
      }
}

// ---------------- fused rel-pos flash attention, split-s x2 ----------------
// scores2[t,s] = (qu[t].k[s] + qv[t].p[1023-|t-s|]) * SCALE2 (log2 domain)
__global__ __launch_bounds__(256)
void attn_kernel(const short* __restrict__ qu, const short* __restrict__ qv,
                 const short* __restrict__ kmat, const short* __restrict__ vt,
                 const short* __restrict__ p,
                 float* __restrict__ Opart, float* __restrict__ marr,
                 float* __restrict__ larr)
{
  __shared__ __align__(16) short Ks[64 * 64];   // [s_loc][dk], swizzled
  __shared__ __align__(16) short Vs[64 * 64];   // [dv][s_loc], swizzled
  __shared__ __align__(16) short Bl[4 * 2048];  // per-wave 16 x 128 circular, swizzled
  __shared__ __align__(16) short Pl[4 * 1024];  // per-wave 16 x 64, swizzled

  // XCD swizzle: contiguous 128 blocks (one (b,sh) slice, 8 heads' K/V) per XCD
  const int nB = blockIdx.x;
  const int o = (nB & 7) * 128 + (nB >> 3);
  const int t0 = (o & 15) * 64;
  const int h = (o >> 4) & 15;
  const int z = o >> 8;
  const int b = z >> 1, sh = z & 1;

  const int tid = threadIdx.x;
  const int wave = tid >> 6, lane = tid & 63;
  const int q15 = lane & 15, q4 = lane >> 4;
  const size_t bh = (size_t)(b * 16 + h);
  const short* pW = p + (size_t)h * 65536;
  const int rl = lane >> 3;
  const int cswz = ((lane & 7) * 16) ^ (rl << 4);
  const int rswz = (q15 & 7) << 4;
  const int swB = q4 << 5;
  char* BlW = (char*)Bl + wave * 4096;
  char* PlW = (char*)Pl + wave * 2048;

  bf16x8 quf[2], qvf[2];
  {
    size_t base = (bh * 1024 + t0 + wave * 16 + q15) * 64 + q4 * 8;
    quf[0] = *(const bf16x8*)(qu + base);
    quf[1] = *(const bf16x8*)(qu + base + 32);
    qvf[0] = *(const bf16x8*)(qv + base);
    qvf[1] = *(const bf16x8*)(qv + base + 32);
  }

  f32x4 acco[4];
#pragma unroll
  for (int g = 0; g < 4; ++g) acco[g] = (f32x4){0.f, 0.f, 0.f, 0.f};
  float mrun[4], lrun[4];
#pragma unroll
  for (int r = 0; r < 4; ++r) { mrun[r] = -1e30f; lrun[r] = 0.f; }

  int live0 = -1, live1 = -1;

  auto refill = [&](int base) {
    f32x4 bacc[4];
#pragma unroll
    for (int g = 0; g < 4; ++g) bacc[g] = (f32x4){0.f, 0.f, 0.f, 0.f};
#pragma unroll
    for (int kc = 0; kc < 2; ++kc) {
      const int kof = kc * 32 + q4 * 8;
#pragma unroll
      for (int g = 0; g < 4; ++g) {
        bf16x8 pf = *(const bf16x8*)(pW + (size_t)(base + g * 16 + q15) * 64 + kof);
        bacc[g] = __builtin_amdgcn_mfma_f32_16x16x32_bf16(qvf[kc], pf, bacc[g], 0, 0, 0);
      }
    }
#pragma unroll
    for (int g = 0; g < 4; ++g)
#pragma unroll
      for (int r = 0; r < 4; ++r) {
        int colb = (((base & 64) + g * 16 + q15) << 1) ^ swB;
        *(short*)(BlW + (q4 * 4 + r) * 256 + colb) = f2b(bacc[g][r]);
      }
  };

  const int sbeg = sh * 512;
  for (int s0 = sbeg; s0 < sbeg + 512; s0 += 64) {
    __syncthreads();
#pragma unroll
    for (int s = 0; s < 4; ++s) {
      int idx = wave * 4 + s;
      if (idx < 8) {
        int row = idx * 8 + rl;
        GLDS(kmat + (bh * 1024 + s0 + row) * 64 + (cswz >> 1), (char*)Ks + idx * 1024);
      } else {
        int i2 = idx - 8;
        int row = i2 * 8 + rl;
        GLDS(vt + ((bh * 64 + row) * 1024 + s0) + (cswz >> 1), (char*)Vs + i2 * 1024);
      }
    }
    __syncthreads();

    // AC = qu . K^T
    f32x4 accac[4];
#pragma unroll
    for (int g = 0; g < 4; ++g) accac[g] = (f32x4){0.f, 0.f, 0.f, 0.f};
#pragma unroll
    for (int kc = 0; kc < 2; ++kc) {
      const int kbyte = kc * 64 + q4 * 16;
#pragma unroll
      for (int g = 0; g < 4; ++g) {
        bf16x8 kf = *(const bf16x8*)((const char*)Ks + (g * 16 + q15) * 128 + (kbyte ^ rswz));
        accac[g] = __builtin_amdgcn_mfma_f32_16x16x32_bf16(quf[kc], kf, accac[g], 0, 0, 0);
      }
    }

    // BD circular-window maintenance (wave-uniform)
    const int dist0 = (t0 > s0) ? (t0 - s0) : (s0 - t0);
    const int jbase = 960 - dist0;
    {
      int sl = (jbase >> 6) & 1;
      bool nd = sl ? (live1 != jbase) : (live0 != jbase);
      if (nd) { refill(jbase); if (sl) live1 = jbase; else live0 = jbase; }
      int b1 = jbase + 64;
      if (b1 <= 960) {
        int sl1 = sl ^ 1;
        bool nd1 = sl1 ? (live1 != b1) : (live0 != b1);
        if (nd1) { refill(b1); if (sl1) live1 = b1; else live0 = b1; }
      }
    }

    // scores: gather BD from circular window + online softmax (log2 domain)
    const int e0 = t0 + wave * 16 + q4 * 4 - s0 - q15;  // tt-ss = e0 + r - 16g
    float pvv[4][4], rmax[4];
#pragma unroll
    for (int r = 0; r < 4; ++r) rmax[r] = -1e30f;
#pragma unroll
    for (int g = 0; g < 4; ++g)
#pragma unroll
      for (int r = 0; r < 4; ++r) {
        int diff = e0 + r - (g << 4);
        int d = diff < 0 ? -diff : diff;
        int colb = (((1023 - d) & 127) << 1) ^ swB;
        float bd = b2f(*(const short*)(BlW + (q4 * 4 + r) * 256 + colb));
        float sc = (accac[g][r] + bd) * SCALE2;
        pvv[g][r] = sc;
        rmax[r] = fmaxf(rmax[r], sc);
      }
#pragma unroll
    for (int m = 1; m < 16; m <<= 1)
#pragma unroll
      for (int r = 0; r < 4; ++r) rmax[r] = fmaxf(rmax[r], __shfl_xor(rmax[r], m));

    // defer-max: rescale only if some row's max grew past threshold
    bool grow = false;
#pragma unroll
    for (int r = 0; r < 4; ++r) grow = grow || (rmax[r] > mrun[r] + 8.0f);
    if (__any(grow)) {
#pragma unroll
      for (int r = 0; r < 4; ++r) {
        float mn = fmaxf(mrun[r], rmax[r]);
        float sc2 = exp2f(mrun[r] - mn);
        mrun[r] = mn;
        lrun[r] *= sc2;
#pragma unroll
        for (int g = 0; g < 4; ++g) acco[g][r] *= sc2;
      }
    }
    float rsum[4];
#pragma unroll
    for (int r = 0; r < 4; ++r) {
      float s_ = 0.f;
#pragma unroll
      for (int g = 0; g < 4; ++g) { pvv[g][r] = exp2f(pvv[g][r] - mrun[r]); s_ += pvv[g][r]; }
      rsum[r] = s_;
    }
#pragma unroll
    for (int m = 1; m < 16; m <<= 1)
#pragma unroll
      for (int r = 0; r < 4; ++r) rsum[r] += __shfl_xor(rsum[r], m);
#pragma unroll
    for (int r = 0; r < 4; ++r) lrun[r] += rsum[r];

    // P -> LDS (bf16, swizzled)
#pragma unroll
    for (int g = 0; g < 4; ++g)
#pragma unroll
      for (int r = 0; r < 4; ++r) {
        int locR = q4 * 4 + r;
        *(short*)(PlW + locR * 128 + (((g * 16 + q15) * 2) ^ ((locR & 7) << 4))) = f2b(pvv[g][r]);
      }

    // O += P.V
#pragma unroll
    for (int kc = 0; kc < 2; ++kc) {
      const int kbyte = kc * 64 + q4 * 16;
      bf16x8 pf = *(const bf16x8*)((const char*)PlW + q15 * 128 + (kbyte ^ rswz));
#pragma unroll
      for (int g = 0; g < 4; ++g) {
        bf16x8 vf = *(const bf16x8*)((const char*)Vs + (g * 16 + q15) * 128 + (kbyte ^ rswz));
        acco[g] = __builtin_amdgcn_mfma_f32_16x16x32_bf16(pf, vf, acco[g], 0, 0, 0);
      }
    }
  }

  // partial outputs (unnormalized O, running m/l)
  size_t obase = ((size_t)(sh * 2 + b) * 16 + h) * 1024;
#pragma unroll
  for (int g = 0; g < 4; ++g)
#pragma unroll
    for (int r = 0; r < 4; ++r) {
      int tt = t0 + wave * 16 + q4 * 4 + r;
      Opart[(obase + tt) * 64 + g * 16 + q15] = acco[g][r];
    }
  if (q15 == 0)
#pragma unroll
    for (int r = 0; r < 4; ++r) {
      int tt = t0 + wave * 16 + q4 * 4 + r;
      marr[obase + tt] = mrun[r];
      larr[obase + tt] = lrun[r];
    }
}

// ---------------- combine split-s halves ----------------
__global__ void combine_k(const float* __restrict__ O, const float* __restrict__ marr,
                          const float* __restrict__ larr, short* __restrict__ x)
{
  int i = blockIdx.x * 256 + threadIdx.x;
  int dv4 = i & 15, rest = i >> 4;
  float4 a0 = *(const float4*)(O + (size_t)rest * 64 + dv4 * 4);
  float4 a1 = *(const float4*)(O + 2097152 + (size_t)rest * 64 + dv4 * 4);
  float m0 = marr[rest], m1 = marr[32768 + rest];
  float l0 = larr[rest], l1 = larr[32768 + rest];
  float mm = fmaxf(m0, m1);
  float w0 = exp2f(m0 - mm), w1 = exp2f(m1 - mm);
  float inv = 1.0f / (l0 * w0 + l1 * w1);
  int bq = rest >> 14, hq = (rest >> 10) & 15, tq = rest & 1023;
  short4v o;
  o[0] = f2b((a0.x * w0 + a1.x * w1) * inv);
  o[1] = f2b((a0.y * w0 + a1.y * w1) * inv);
  o[2] = f2b((a0.z * w0 + a1.z * w1) * inv);
  o[3] = f2b((a0.w * w0 + a1.w * w1) * inv);
  *(short4v*)(x + ((size_t)(bq * 1024 + tq) * 1024 + hq * 64 + dv4 * 4)) = o;
}

// ---------------- launch ----------------
extern "C" void kernel_launch(void* const* d_in, const int* in_sizes, int n_in,
                              void* d_out, int out_size, void* d_ws, size_t ws_size,
                              hipStream_t stream) {
  const float* query = (const float*)d_in[0];
  const float* key   = (const float*)d_in[1];
  const float* value = (const float*)d_in[2];
  const float* pos   = (const float*)d_in[3];
  const float* Wq = (const float*)d_in[4];  const float* bq = (const float*)d_in[5];
  const float* Wk = (const float*)d_in[6];  const float* bk = (const float*)d_in[7];
  const float* Wv = (const float*)d_in[8];  const float* bv = (const float*)d_in[9];
  const float* Wp = (const float*)d_in[10]; const float* bp = (const float*)d_in[11];
  const float* Wo = (const float*)d_in[12]; const float* bo = (const float*)d_in[13];
  const float* ub = (const float*)d_in[14]; const float* vb = (const float*)d_in[15];

  char* ws = (char*)d_ws;
  const size_t MB = 1 << 20;
  short* Wo_bf    = (short*)(ws);            // 2MB
  short* qu_bf    = (short*)(ws + 2 * MB);   // 4MB
  short* qv_bf    = (short*)(ws + 6 * MB);   // 4MB
  short* k_bf     = (short*)(ws + 10 * MB);  // 4MB
  short* vT_bf    = (short*)(ws + 14 * MB);  // 4MB
  short* p_bf     = (short*)(ws + 18 * MB);  // 2MB
  short* x_bf     = (short*)(ws + 20 * MB);  // 4MB
  short* query_bf = (short*)(ws + 24 * MB);  // 4MB  (dead after gemm_qkvp)
  short* key_bf   = (short*)(ws + 28 * MB);  // 4MB
  short* value_bf = (short*)(ws + 32 * MB);  // 4MB
  short* pos_bf   = (short*)(ws + 36 * MB);  // 2MB
  short* Wq_bf    = (short*)(ws + 38 * MB);  // 2MB
  short* Wk_bf    = (short*)(ws + 40 * MB);  // 2MB
  short* Wv_bf    = (short*)(ws + 42 * MB);  // 2MB
  short* Wp_bf    = (short*)(ws + 44 * MB);  // 2MB -> 46MB total
  // aliases (written after their underlying buffers are dead)
  float* Opart = (float*)(ws + 24 * MB);     // 16MB over query/key/value/pos
  float* marr  = (float*)(ws + 40 * MB);     // 256KB over Wk_bf
  float* larr  = (float*)(ws + 40 * MB + 256 * 1024);

  CvtTab tab;
  tab.s[0] = query;           tab.d[0] = query_bf;
  tab.s[1] = query + 1048576; tab.d[1] = query_bf + 1048576;
  tab.s[2] = key;             tab.d[2] = key_bf;
  tab.s[3] = key + 1048576;   tab.d[3] = key_bf + 1048576;
  tab.s[4] = value;           tab.d[4] = value_bf;
  tab.s[5] = value + 1048576; tab.d[5] = value_bf + 1048576;
  tab.s[6] = pos;             tab.d[6] = pos_bf;
  tab.s[7] = Wq;              tab.d[7] = Wq_bf;
  tab.s[8] = Wk;              tab.d[8] = Wk_bf;
  tab.s[9] = Wv;              tab.d[9] = Wv_bf;
  tab.s[10] = Wp;             tab.d[10] = Wp_bf;
  tab.s[11] = Wo;             tab.d[11] = Wo_bf;
  hipLaunchKernelGGL(cvt_all, dim3(12288), dim3(256), 0, stream, tab);

  hipLaunchKernelGGL(gemm_qkvp, dim3(448), dim3(256), 0, stream,
                     query_bf, key_bf, value_bf, pos_bf,
                     Wq_bf, Wk_bf, Wv_bf, Wp_bf,
                     bq, bk, bv, bp, ub, vb,
                     qu_bf, qv_bf, k_bf, vT_bf, p_bf);

  hipLaunchKernelGGL(attn_kernel, dim3(1024), dim3(256), 0, stream,
                     qu_bf, qv_bf, k_bf, vT_bf, p_bf, Opart, marr, larr);

  hipLaunchKernelGGL(combine_k, dim3(2048), dim3(256), 0, stream,
                     Opart, marr, larr, x_bf);

  hipLaunchKernelGGL(gemm_out, dim3(256), dim3(256), 0, stream,
                     x_bf, Wo_bf, bo, (float*)d_out);
}

// Round 4
// 129.651 us; speedup vs baseline: 3.4042x; 1.0638x over previous
//
#include <hip/hip_runtime.h>
#include <hip/hip_bf16.h>
#include <stdint.h>

typedef __attribute__((ext_vector_type(8))) short bf16x8;
typedef __attribute__((ext_vector_type(4))) float f32x4;
typedef __attribute__((ext_vector_type(4))) short short4v;

#define SCALE2 0.18033688011112042f  /* (1/8) * log2(e) */

__device__ __forceinline__ short f2b(float f) {
  union { float f; unsigned u; } un; un.f = f;
  unsigned r = un.u + 0x7FFFu + ((un.u >> 16) & 1u);
  return (short)(r >> 16);
}
__device__ __forceinline__ float b2f(short s) {
  union { unsigned u; float f; } un; un.u = ((unsigned)(unsigned short)s) << 16;
  return un.f;
}

// async global->LDS, 16B per lane; LDS dest is wave-uniform base + lane*16
#define GLDS(GP, LP) __builtin_amdgcn_global_load_lds( \
    (__attribute__((address_space(1))) void*)(GP), \
    (__attribute__((address_space(3))) void*)(LP), 16, 0, 0)

// ---------------- fused f32 -> bf16 conversion ----------------
struct CvtTab { const float* s[12]; short* d[12]; };

__global__ void cvt_all(CvtTab tab) {
  int chunk = blockIdx.x >> 10;
  int off = (blockIdx.x & 1023) * 256 + threadIdx.x;
  float4 v = *((const float4*)tab.s[chunk] + off);
  short4v o;
  o[0] = f2b(v.x); o[1] = f2b(v.y); o[2] = f2b(v.z); o[3] = f2b(v.w);
  *((short4v*)tab.d[chunk] + off) = o;
}

// ---------------- 128x128 bf16 GEMM core, K=1024, 2-phase dbuf ----------------
__device__ __forceinline__ void gemm_core128(
    const short* __restrict__ A, const short* __restrict__ W,
    int tile_m, int tile_n, short* lds, f32x4 acc[4][4])
{
  const int tid = threadIdx.x;
  const int wave = tid >> 6, lane = tid & 63;
  const int wr = wave >> 1, wc = wave & 1;
  const int q15 = lane & 15, q4 = lane >> 4;
  const int rl = lane >> 3;
  const int cswz = ((lane & 7) * 16) ^ (rl << 4);

#pragma unroll
  for (int i = 0; i < 4; ++i)
#pragma unroll
    for (int j = 0; j < 4; ++j) acc[i][j] = (f32x4){0.f, 0.f, 0.f, 0.f};

  auto stage = [&](int buf, int k0) {
    short* As = lds + buf * 16384;
    short* Bs = As + 8192;
#pragma unroll
    for (int s = 0; s < 4; ++s) {
      int ia = wave * 4 + s;
      int row = ia * 8 + rl;
      GLDS(A + (size_t)(tile_m + row) * 1024 + k0 + (cswz >> 1), (char*)As + ia * 1024);
      GLDS(W + (size_t)(tile_n + row) * 1024 + k0 + (cswz >> 1), (char*)Bs + ia * 1024);
    }
  };

  stage(0, 0);
  __syncthreads();
  for (int t = 0; t < 16; ++t) {
    const int cur = t & 1;
    if (t < 15) stage(cur ^ 1, (t + 1) * 64);
    const short* As = lds + cur * 16384;
    const short* Bs = As + 8192;
#pragma unroll
    for (int kk = 0; kk < 2; ++kk) {
      const int kbyte = kk * 64 + q4 * 16;
      const int rswz = (q15 & 7) << 4;
      bf16x8 af[4], bfr[4];
#pragma unroll
      for (int i = 0; i < 4; ++i)
        af[i] = *(const bf16x8*)((const char*)As + (wr * 64 + i * 16 + q15) * 128 + (kbyte ^ rswz));
#pragma unroll
      for (int j = 0; j < 4; ++j)
        bfr[j] = *(const bf16x8*)((const char*)Bs + (wc * 64 + j * 16 + q15) * 128 + (kbyte ^ rswz));
#pragma unroll
      for (int i = 0; i < 4; ++i)
#pragma unroll
        for (int j = 0; j < 4; ++j)
          acc[i][j] = __builtin_amdgcn_mfma_f32_16x16x32_bf16(af[i], bfr[j], acc[i][j], 0, 0, 0);
    }
    __syncthreads();
  }
}

// ---------------- stacked QKVP projection GEMM ----------------
__global__ __launch_bounds__(256)
void gemm_qkvp(const short* __restrict__ q_in, const short* __restrict__ k_in,
               const short* __restrict__ v_in, const short* __restrict__ p_in,
               const short* __restrict__ wq, const short* __restrict__ wk,
               const short* __restrict__ wv, const short* __restrict__ wp,
               const float* __restrict__ bq, const float* __restrict__ bk,
               const float* __restrict__ bv, const float* __restrict__ bp,
               const float* __restrict__ ub, const float* __restrict__ vb,
               short* __restrict__ qu, short* __restrict__ qv,
               short* __restrict__ kx, short* __restrict__ vtp, short* __restrict__ pp)
{
  __shared__ __align__(16) short lds[32768];
  const int n = blockIdx.x;
  const int by = n & 7;
  const int bx = n >> 3;
  const short* A; const short* W; const float* bias; int tm, mode;
  if (bx < 16)      { A = q_in; W = wq; bias = bq; tm = bx;      mode = 0; }
  else if (bx < 32) { A = k_in; W = wk; bias = bk; tm = bx - 16; mode = 1; }
  else if (bx < 48) { A = v_in; W = wv; bias = bv; tm = bx - 32; mode = 2; }
  else              { A = p_in; W = wp; bias = bp; tm = bx - 48; mode = 3; }

  f32x4 acc[4][4];
  gemm_core128(A, W, tm * 128, by * 128, lds, acc);

  const int lane = threadIdx.x & 63, wave = threadIdx.x >> 6;
  const int wr = wave >> 1, wc = wave & 1, q15 = lane & 15, q4 = lane >> 4;
#pragma unroll
  for (int i = 0; i < 4; ++i)
#pragma unroll
    for (int j = 0; j < 4; ++j)
#pragma unroll
      for (int r = 0; r < 4; ++r) {
        int m = tm * 128 + wr * 64 + i * 16 + q4 * 4 + r;
        int nn = by * 128 + wc * 64 + j * 16 + q15;
        float v = acc[i][j][r] + bias[nn];
        int bb = m >> 10, t = m & 1023, hh = nn >> 6, d = nn & 63;
        if (mode == 0) {
          size_t o = ((size_t)(bb * 16 + hh) * 1024 + t) * 64 + d;
          qu[o] = f2b((v + ub[nn]) * SCALE2);   // pre-scale: MFMA produces scores in log2 units
          qv[o] = f2b((v + vb[nn]) * SCALE2);
        } else if (mode == 1) {
          kx[((size_t)(bb * 16 + hh) * 1024 + t) * 64 + d] = f2b(v);
        } else if (mode == 2) {
          vtp[((size_t)(bb * 16 + hh) * 64 + d) * 1024 + t] = f2b(v);
        } else {
          pp[((size_t)hh * 1024 + m) * 64 + d] = f2b(v);
        }
      }
}

// ---------------- output GEMM, 128x64 tiles (256 blocks), f32 out ----------------
__global__ __launch_bounds__(256)
void gemm_out(const short* __restrict__ X, const short* __restrict__ W,
              const float* __restrict__ bo, float* __restrict__ out)
{
  __shared__ __align__(16) short lds[24576];
  const int n = blockIdx.x;
  const int bxm = (n >> 3) & 15;
  const int byn = ((n & 7) << 1) | (n >> 7);
  const int tile_m = bxm * 128, tile_n = byn * 64;

  const int tid = threadIdx.x;
  const int wave = tid >> 6, lane = tid & 63;
  const int wr = wave >> 1, wc = wave & 1;
  const int q15 = lane & 15, q4 = lane >> 4;
  const int rl = lane >> 3;
  const int cswz = ((lane & 7) * 16) ^ (rl << 4);

  f32x4 acc[4][2];
#pragma unroll
  for (int i = 0; i < 4; ++i)
#pragma unroll
    for (int j = 0; j < 2; ++j) acc[i][j] = (f32x4){0.f, 0.f, 0.f, 0.f};

  auto stage = [&](int buf, int k0) {
    short* As = lds + buf * 12288;
    short* Bs = As + 8192;
#pragma unroll
    for (int s = 0; s < 6; ++s) {
      int idx = wave * 6 + s;
      if (idx < 16) {
        int row = idx * 8 + rl;
        GLDS(X + (size_t)(tile_m + row) * 1024 + k0 + (cswz >> 1), (char*)As + idx * 1024);
      } else {
        int i2 = idx - 16;
        int row = i2 * 8 + rl;
        GLDS(W + (size_t)(tile_n + row) * 1024 + k0 + (cswz >> 1), (char*)Bs + i2 * 1024);
      }
    }
  };

  stage(0, 0);
  __syncthreads();
  for (int t = 0; t < 16; ++t) {
    const int cur = t & 1;
    if (t < 15) stage(cur ^ 1, (t + 1) * 64);
    const short* As = lds + cur * 12288;
    const short* Bs = As + 8192;
#pragma unroll
    for (int kk = 0; kk < 2; ++kk) {
      const int kbyte = kk * 64 + q4 * 16;
      const int rswz = (q15 & 7) << 4;
      bf16x8 af[4], bfr[2];
#pragma unroll
      for (int i = 0; i < 4; ++i)
        af[i] = *(const bf16x8*)((const char*)As + (wr * 64 + i * 16 + q15) * 128 + (kbyte ^ rswz));
#pragma unroll
      for (int j = 0; j < 2; ++j)
        bfr[j] = *(const bf16x8*)((const char*)Bs + (wc * 32 + j * 16 + q15) * 128 + (kbyte ^ rswz));
#pragma unroll
      for (int i = 0; i < 4; ++i)
#pragma unroll
        for (int j = 0; j < 2; ++j)
          acc[i][j] = __builtin_amdgcn_mfma_f32_16x16x32_bf16(af[i], bfr[j], acc[i][j], 0, 0, 0);
    }
    __syncthreads();
  }

#pragma unroll
  for (int i = 0; i < 4; ++i)
#pragma unroll
    for (int j = 0; j < 2; ++j)
#pragma unroll
      for (int r = 0; r < 4; ++r) {
        int m = tile_m + wr * 64 + i * 16 + q4 * 4 + r;
        int nn = tile_n + wc * 32 + j * 16 + q15;
        out[(size_t)m * 1024 + nn] = acc[i][j][r] + bo[nn];
      }
}

// ---------------- fused rel-pos flash attention, split-s x2, no-max softmax ----------------
// scores2[t,s] = qu_s[t].k[s] + qv_s[t].p[1023-|t-s|]   (already in log2 units)
__global__ __launch_bounds__(256, 4)
void attn_kernel(const short* __restrict__ qu, const short* __restrict__ qv,
                 const short* __restrict__ kmat, const short* __restrict__ vt,
                 const short* __restrict__ p,
                 float* __restrict__ Opart, float* __restrict__ larr)
{
  __shared__ __align__(16) short Ks[4096];      // [s_loc][dk], xor-swizzled
  __shared__ __align__(16) short Vs[4096];      // [dv][s_loc], xor-swizzled
  __shared__ __align__(16) short Bl[4 * 2048];  // per-wave 16x128 circular, rotated
  __shared__ __align__(16) short Pl[4 * 1024];  // per-wave 16x64, xor-swizzled

  // XCD swizzle: contiguous 128 blocks (one (b,sh) slice, 8 heads' K/V) per XCD
  const int nB = blockIdx.x;
  const int o = (nB & 7) * 128 + (nB >> 3);
  const int t0 = (o & 15) * 64;
  const int h = (o >> 4) & 15;
  const int z = o >> 8;
  const int b = z >> 1, sh = z & 1;

  const int tid = threadIdx.x;
  const int wave = tid >> 6, lane = tid & 63;
  const int q15 = lane & 15, q4 = lane >> 4;
  const size_t bh = (size_t)(b * 16 + h);
  const short* pW = p + (size_t)h * 65536;
  const int rswz = (q15 & 7) << 4;
  char* BlW = (char*)Bl + wave * 4096;
  char* PlW = (char*)Pl + wave * 2048;

  // ---- staging geometry (reg-staged K/V, T14) ----
  const int srow = tid >> 3;            // 0..31
  const int scol = (tid & 7) * 8;       // element col (x8 shorts)
  const int sdst = srow * 128 + ((scol * 2) ^ ((srow & 7) << 4));  // LDS byte dest

  const int sbeg = sh * 512, send = sbeg + 512;
  const short* kg = kmat + (bh * 1024 + sbeg + srow) * 64 + scol;       // +32 rows: +2048
  const short* vg = vt + (bh * 64 + srow) * 1024 + sbeg + scol;         // +32 rows: +32768

  bf16x8 quf[2], qvf[2];
  {
    size_t base = (bh * 1024 + t0 + wave * 16 + q15) * 64 + q4 * 8;
    quf[0] = *(const bf16x8*)(qu + base);
    quf[1] = *(const bf16x8*)(qu + base + 32);
    qvf[0] = *(const bf16x8*)(qv + base);
    qvf[1] = *(const bf16x8*)(qv + base + 32);
  }

  f32x4 acco[4];
#pragma unroll
  for (int g = 0; g < 4; ++g) acco[g] = (f32x4){0.f, 0.f, 0.f, 0.f};
  float lrun[4] = {0.f, 0.f, 0.f, 0.f};

  int live0 = -1, live1 = -1;

  auto refill = [&](int base) {
    f32x4 bacc[4];
#pragma unroll
    for (int g = 0; g < 4; ++g) bacc[g] = (f32x4){0.f, 0.f, 0.f, 0.f};
#pragma unroll
    for (int kc = 0; kc < 2; ++kc) {
      const int kof = kc * 32 + q4 * 8;
#pragma unroll
      for (int g = 0; g < 4; ++g) {
        bf16x8 pf = *(const bf16x8*)(pW + (size_t)(base + g * 16 + q15) * 64 + kof);
        bacc[g] = __builtin_amdgcn_mfma_f32_16x16x32_bf16(qvf[kc], pf, bacc[g], 0, 0, 0);
      }
    }
#pragma unroll
    for (int g = 0; g < 4; ++g)
#pragma unroll
      for (int r = 0; r < 4; ++r) {
        int phys = ((base & 64) + g * 16 + q15 + q4 * 16) & 127;   // rotation layout
        *(short*)(BlW + (q4 * 4 + r) * 256 + phys * 2) = f2b(bacc[g][r]);
      }
  };

  // prologue: load tile 0 into regs
  bf16x8 kr0 = *(const bf16x8*)kg;
  bf16x8 kr1 = *(const bf16x8*)(kg + 2048);
  bf16x8 vr0 = *(const bf16x8*)vg;
  bf16x8 vr1 = *(const bf16x8*)(vg + 32768);

  for (int s0 = sbeg; s0 < send; s0 += 64) {
    __syncthreads();
    *(bf16x8*)((char*)Ks + sdst) = kr0;
    *(bf16x8*)((char*)Ks + sdst + 4096) = kr1;
    *(bf16x8*)((char*)Vs + sdst) = vr0;
    *(bf16x8*)((char*)Vs + sdst + 4096) = vr1;
    __syncthreads();
    if (s0 + 64 < send) {   // issue next tile's loads; latency hides under compute
      kg += 4096; vg += 64;
      kr0 = *(const bf16x8*)kg;
      kr1 = *(const bf16x8*)(kg + 2048);
      vr0 = *(const bf16x8*)vg;
      vr1 = *(const bf16x8*)(vg + 32768);
    }

    // AC = qu_s . K^T
    f32x4 accac[4];
#pragma unroll
    for (int g = 0; g < 4; ++g) accac[g] = (f32x4){0.f, 0.f, 0.f, 0.f};
#pragma unroll
    for (int kc = 0; kc < 2; ++kc) {
      const int kbyte = kc * 64 + q4 * 16;
#pragma unroll
      for (int g = 0; g < 4; ++g) {
        bf16x8 kf = *(const bf16x8*)((const char*)Ks + (g * 16 + q15) * 128 + (kbyte ^ rswz));
        accac[g] = __builtin_amdgcn_mfma_f32_16x16x32_bf16(quf[kc], kf, accac[g], 0, 0, 0);
      }
    }

    // BD circular-window maintenance (block-uniform)
    const int dist0 = (t0 > s0) ? (t0 - s0) : (s0 - t0);
    const int jbase = 960 - dist0;
    {
      int sl = (jbase >> 6) & 1;
      bool nd = sl ? (live1 != jbase) : (live0 != jbase);
      if (nd) { refill(jbase); if (sl) live1 = jbase; else live0 = jbase; }
      int b1 = jbase + 64;
      if (b1 <= 960) {
        int sl1 = sl ^ 1;
        bool nd1 = sl1 ? (live1 != b1) : (live0 != b1);
        if (nd1) { refill(b1); if (sl1) live1 = b1; else live0 = b1; }
      }
    }

    // scores + exp2 + P-pack; l accumulated per-lane (no per-tile reductions)
    const int rb = q4 * 1024;  // row base bytes (row = 4*q4 + r -> +r*256)
    unsigned pb[4][4];
#define SCORE_ELEM(g, r, ARG) do {                                          \
      int aw = (ARG) & 127;                                                 \
      float bd = b2f(*(const short*)(BlW + rb + (r) * 256 + aw * 2));       \
      float e_ = exp2f(accac[g][r] + bd);                                   \
      unsigned t_ = __float_as_uint(e_) >> 16;                              \
      pb[g][r] = t_;                                                        \
      lrun[r] += __uint_as_float(t_ << 16);                                 \
    } while (0)

    if (s0 < t0) {
      const int C = 1023 - dist0 - wave * 16 + 12 * q4 + q15;
#pragma unroll
      for (int g = 0; g < 4; ++g)
#pragma unroll
        for (int r = 0; r < 4; ++r) SCORE_ELEM(g, r, C + 16 * g - r);
    } else if (s0 > t0) {
      const int C = 1023 - dist0 + wave * 16 + 20 * q4 - q15;
#pragma unroll
      for (int g = 0; g < 4; ++g)
#pragma unroll
        for (int r = 0; r < 4; ++r) SCORE_ELEM(g, r, C + r - 16 * g);
    } else {
      const int e0 = wave * 16 + 4 * q4 - q15;
      const int A = 1023 + 16 * q4;
#pragma unroll
      for (int g = 0; g < 4; ++g)
#pragma unroll
        for (int r = 0; r < 4; ++r) {
          int e = e0 + r - 16 * g;
          int d = e < 0 ? -e : e;
          SCORE_ELEM(g, r, A - d);
        }
    }
#undef SCORE_ELEM

    // P -> LDS (bf16, xor-swizzled)
#pragma unroll
    for (int g = 0; g < 4; ++g)
#pragma unroll
      for (int r = 0; r < 4; ++r) {
        int locR = q4 * 4 + r;
        *(short*)(PlW + locR * 128 + (((g * 16 + q15) * 2) ^ ((locR & 7) << 4))) = (short)pb[g][r];
      }

    // O += P.V
#pragma unroll
    for (int kc = 0; kc < 2; ++kc) {
      const int kbyte = kc * 64 + q4 * 16;
      bf16x8 pf = *(const bf16x8*)((const char*)PlW + q15 * 128 + (kbyte ^ rswz));
#pragma unroll
      for (int g = 0; g < 4; ++g) {
        bf16x8 vf = *(const bf16x8*)((const char*)Vs + (g * 16 + q15) * 128 + (kbyte ^ rswz));
        acco[g] = __builtin_amdgcn_mfma_f32_16x16x32_bf16(pf, vf, acco[g], 0, 0, 0);
      }
    }
  }

  // final l reduction across the 16 s-lanes of each q4 group
#pragma unroll
  for (int m = 1; m < 16; m <<= 1)
#pragma unroll
    for (int r = 0; r < 4; ++r) lrun[r] += __shfl_xor(lrun[r], m);

  size_t obase = ((size_t)(sh * 2 + b) * 16 + h) * 1024;
#pragma unroll
  for (int g = 0; g < 4; ++g)
#pragma unroll
    for (int r = 0; r < 4; ++r) {
      int tt = t0 + wave * 16 + q4 * 4 + r;
      Opart[(obase + tt) * 64 + g * 16 + q15] = acco[g][r];
    }
  if (q15 == 0)
#pragma unroll
    for (int r = 0; r < 4; ++r) {
      int tt = t0 + wave * 16 + q4 * 4 + r;
      larr[obase + tt] = lrun[r];
    }
}

// ---------------- combine split-s halves ----------------
__global__ void combine_k(const float* __restrict__ O, const float* __restrict__ larr,
                          short* __restrict__ x)
{
  int i = blockIdx.x * 256 + threadIdx.x;
  int dv4 = i & 15, rest = i >> 4;
  float4 a0 = *(const float4*)(O + (size_t)rest * 64 + dv4 * 4);
  float4 a1 = *(const float4*)(O + 2097152 + (size_t)rest * 64 + dv4 * 4);
  float l0 = larr[rest], l1 = larr[32768 + rest];
  float inv = 1.0f / (l0 + l1);
  int bq = rest >> 14, hq = (rest >> 10) & 15, tq = rest & 1023;
  short4v o;
  o[0] = f2b((a0.x + a1.x) * inv);
  o[1] = f2b((a0.y + a1.y) * inv);
  o[2] = f2b((a0.z + a1.z) * inv);
  o[3] = f2b((a0.w + a1.w) * inv);
  *(short4v*)(x + ((size_t)(bq * 1024 + tq) * 1024 + hq * 64 + dv4 * 4)) = o;
}

// ---------------- launch ----------------
extern "C" void kernel_launch(void* const* d_in, const int* in_sizes, int n_in,
                              void* d_out, int out_size, void* d_ws, size_t ws_size,
                              hipStream_t stream) {
  const float* query = (const float*)d_in[0];
  const float* key   = (const float*)d_in[1];
  const float* value = (const float*)d_in[2];
  const float* pos   = (const float*)d_in[3];
  const float* Wq = (const float*)d_in[4];  const float* bq = (const float*)d_in[5];
  const float* Wk = (const float*)d_in[6];  const float* bk = (const float*)d_in[7];
  const float* Wv = (const float*)d_in[8];  const float* bv = (const float*)d_in[9];
  const float* Wp = (const float*)d_in[10]; const float* bp = (const float*)d_in[11];
  const float* Wo = (const float*)d_in[12]; const float* bo = (const float*)d_in[13];
  const float* ub = (const float*)d_in[14]; const float* vb = (const float*)d_in[15];

  char* ws = (char*)d_ws;
  const size_t MB = 1 << 20;
  short* Wo_bf    = (short*)(ws);            // 2MB
  short* qu_bf    = (short*)(ws + 2 * MB);   // 4MB
  short* qv_bf    = (short*)(ws + 6 * MB);   // 4MB
  short* k_bf     = (short*)(ws + 10 * MB);  // 4MB
  short* vT_bf    = (short*)(ws + 14 * MB);  // 4MB
  short* p_bf     = (short*)(ws + 18 * MB);  // 2MB
  short* x_bf     = (short*)(ws + 20 * MB);  // 4MB
  short* query_bf = (short*)(ws + 24 * MB);  // 4MB  (dead after gemm_qkvp)
  short* key_bf   = (short*)(ws + 28 * MB);  // 4MB
  short* value_bf = (short*)(ws + 32 * MB);  // 4MB
  short* pos_bf   = (short*)(ws + 36 * MB);  // 2MB
  short* Wq_bf    = (short*)(ws + 38 * MB);  // 2MB
  short* Wk_bf    = (short*)(ws + 40 * MB);  // 2MB
  short* Wv_bf    = (short*)(ws + 42 * MB);  // 2MB
  short* Wp_bf    = (short*)(ws + 44 * MB);  // 2MB -> 46MB total
  // aliases (written after their underlying buffers are dead)
  float* Opart = (float*)(ws + 24 * MB);     // 16MB over query/key/value/pos
  float* larr  = (float*)(ws + 40 * MB);     // 256KB over Wk_bf

  CvtTab tab;
  tab.s[0] = query;           tab.d[0] = query_bf;
  tab.s[1] = query + 1048576; tab.d[1] = query_bf + 1048576;
  tab.s[2] = key;             tab.d[2] = key_bf;
  tab.s[3] = key + 1048576;   tab.d[3] = key_bf + 1048576;
  tab.s[4] = value;           tab.d[4] = value_bf;
  tab.s[5] = value + 1048576; tab.d[5] = value_bf + 1048576;
  tab.s[6] = pos;             tab.d[6] = pos_bf;
  tab.s[7] = Wq;              tab.d[7] = Wq_bf;
  tab.s[8] = Wk;              tab.d[8] = Wk_bf;
  tab.s[9] = Wv;              tab.d[9] = Wv_bf;
  tab.s[10] = Wp;             tab.d[10] = Wp_bf;
  tab.s[11] = Wo;             tab.d[11] = Wo_bf;
  hipLaunchKernelGGL(cvt_all, dim3(12288), dim3(256), 0, stream, tab);

  hipLaunchKernelGGL(gemm_qkvp, dim3(448), dim3(256), 0, stream,
                     query_bf, key_bf, value_bf, pos_bf,
                     Wq_bf, Wk_bf, Wv_bf, Wp_bf,
                     bq, bk, bv, bp, ub, vb,
                     qu_bf, qv_bf, k_bf, vT_bf, p_bf);

  hipLaunchKernelGGL(attn_kernel, dim3(1024), dim3(256), 0, stream,
                     qu_bf, qv_bf, k_bf, vT_bf, p_bf, Opart, larr);

  hipLaunchKernelGGL(combine_k, dim3(2048), dim3(256), 0, stream,
                     Opart, larr, x_bf);

  hipLaunchKernelGGL(gemm_out, dim3(256), dim3(256), 0, stream,
                     x_bf, Wo_bf, bo, (float*)d_out);
}

// Round 5
// 116.684 us; speedup vs baseline: 3.7825x; 1.1111x over previous
//
#include <hip/hip_runtime.h>
#include <hip/hip_bf16.h>
#include <stdint.h>

typedef __attribute__((ext_vector_type(8))) short bf16x8;
typedef __attribute__((ext_vector_type(4))) float f32x4;
typedef __attribute__((ext_vector_type(4))) short short4v;
typedef __attribute__((ext_vector_type(2))) unsigned u32x2;

#define SCALE2 0.18033688011112042f  /* (1/8) * log2(e) */

__device__ __forceinline__ short f2b(float f) {
  union { float f; unsigned u; } un; un.f = f;
  unsigned r = un.u + 0x7FFFu + ((un.u >> 16) & 1u);
  return (short)(r >> 16);
}

// async global->LDS, 16B per lane; LDS dest is wave-uniform base + lane*16
#define GLDS(GP, LP) __builtin_amdgcn_global_load_lds( \
    (__attribute__((address_space(1))) void*)(GP), \
    (__attribute__((address_space(3))) void*)(LP), 16, 0, 0)

// ---------------- fused f32 -> bf16 conversion ----------------
struct CvtTab { const float* s[12]; short* d[12]; };

__global__ void cvt_all(CvtTab tab) {
  int chunk = blockIdx.x >> 10;
  int off = (blockIdx.x & 1023) * 256 + threadIdx.x;
  float4 v = *((const float4*)tab.s[chunk] + off);
  short4v o;
  o[0] = f2b(v.x); o[1] = f2b(v.y); o[2] = f2b(v.z); o[3] = f2b(v.w);
  *((short4v*)tab.d[chunk] + off) = o;
}

// ---------------- 128x128 bf16 GEMM core, K=1024, 2-phase dbuf ----------------
__device__ __forceinline__ void gemm_core128(
    const short* __restrict__ A, const short* __restrict__ W,
    int tile_m, int tile_n, short* lds, f32x4 acc[4][4])
{
  const int tid = threadIdx.x;
  const int wave = tid >> 6, lane = tid & 63;
  const int wr = wave >> 1, wc = wave & 1;
  const int q15 = lane & 15, q4 = lane >> 4;
  const int rl = lane >> 3;
  const int cswz = ((lane & 7) * 16) ^ (rl << 4);

#pragma unroll
  for (int i = 0; i < 4; ++i)
#pragma unroll
    for (int j = 0; j < 4; ++j) acc[i][j] = (f32x4){0.f, 0.f, 0.f, 0.f};

  auto stage = [&](int buf, int k0) {
    short* As = lds + buf * 16384;
    short* Bs = As + 8192;
#pragma unroll
    for (int s = 0; s < 4; ++s) {
      int ia = wave * 4 + s;
      int row = ia * 8 + rl;
      GLDS(A + (size_t)(tile_m + row) * 1024 + k0 + (cswz >> 1), (char*)As + ia * 1024);
      GLDS(W + (size_t)(tile_n + row) * 1024 + k0 + (cswz >> 1), (char*)Bs + ia * 1024);
    }
  };

  stage(0, 0);
  __syncthreads();
  for (int t = 0; t < 16; ++t) {
    const int cur = t & 1;
    if (t < 15) stage(cur ^ 1, (t + 1) * 64);
    const short* As = lds + cur * 16384;
    const short* Bs = As + 8192;
#pragma unroll
    for (int kk = 0; kk < 2; ++kk) {
      const int kbyte = kk * 64 + q4 * 16;
      const int rswz = (q15 & 7) << 4;
      bf16x8 af[4], bfr[4];
#pragma unroll
      for (int i = 0; i < 4; ++i)
        af[i] = *(const bf16x8*)((const char*)As + (wr * 64 + i * 16 + q15) * 128 + (kbyte ^ rswz));
#pragma unroll
      for (int j = 0; j < 4; ++j)
        bfr[j] = *(const bf16x8*)((const char*)Bs + (wc * 64 + j * 16 + q15) * 128 + (kbyte ^ rswz));
#pragma unroll
      for (int i = 0; i < 4; ++i)
#pragma unroll
        for (int j = 0; j < 4; ++j)
          acc[i][j] = __builtin_amdgcn_mfma_f32_16x16x32_bf16(af[i], bfr[j], acc[i][j], 0, 0, 0);
    }
    __syncthreads();
  }
}

// ---------------- stacked QKVP projection GEMM ----------------
__global__ __launch_bounds__(256)
void gemm_qkvp(const short* __restrict__ q_in, const short* __restrict__ k_in,
               const short* __restrict__ v_in, const short* __restrict__ p_in,
               const short* __restrict__ wq, const short* __restrict__ wk,
               const short* __restrict__ wv, const short* __restrict__ wp,
               const float* __restrict__ bq, const float* __restrict__ bk,
               const float* __restrict__ bv, const float* __restrict__ bp,
               const float* __restrict__ ub, const float* __restrict__ vb,
               short* __restrict__ qu, short* __restrict__ qv,
               short* __restrict__ kx, short* __restrict__ vtp, short* __restrict__ pp)
{
  __shared__ __align__(16) short lds[32768];
  const int n = blockIdx.x;
  const int by = n & 7;
  const int bx = n >> 3;
  const short* A; const short* W; const float* bias; int tm, mode;
  if (bx < 16)      { A = q_in; W = wq; bias = bq; tm = bx;      mode = 0; }
  else if (bx < 32) { A = k_in; W = wk; bias = bk; tm = bx - 16; mode = 1; }
  else if (bx < 48) { A = v_in; W = wv; bias = bv; tm = bx - 32; mode = 2; }
  else              { A = p_in; W = wp; bias = bp; tm = bx - 48; mode = 3; }

  f32x4 acc[4][4];
  gemm_core128(A, W, tm * 128, by * 128, lds, acc);

  const int lane = threadIdx.x & 63, wave = threadIdx.x >> 6;
  const int wr = wave >> 1, wc = wave & 1, q15 = lane & 15, q4 = lane >> 4;
#pragma unroll
  for (int i = 0; i < 4; ++i)
#pragma unroll
    for (int j = 0; j < 4; ++j)
#pragma unroll
      for (int r = 0; r < 4; ++r) {
        int m = tm * 128 + wr * 64 + i * 16 + q4 * 4 + r;
        int nn = by * 128 + wc * 64 + j * 16 + q15;
        float v = acc[i][j][r] + bias[nn];
        int bb = m >> 10, t = m & 1023, hh = nn >> 6, d = nn & 63;
        if (mode == 0) {
          size_t o = ((size_t)(bb * 16 + hh) * 1024 + t) * 64 + d;
          qu[o] = f2b((v + ub[nn]) * SCALE2);   // pre-scale: scores come out in log2 units
          qv[o] = f2b((v + vb[nn]) * SCALE2);
        } else if (mode == 1) {
          kx[((size_t)(bb * 16 + hh) * 1024 + t) * 64 + d] = f2b(v);
        } else if (mode == 2) {
          vtp[((size_t)(bb * 16 + hh) * 64 + d) * 1024 + t] = f2b(v);
        } else {
          pp[((size_t)hh * 1024 + m) * 64 + d] = f2b(v);
        }
      }
}

// ---------------- output GEMM, 128x64 tiles (256 blocks), f32 out ----------------
__global__ __launch_bounds__(256)
void gemm_out(const short* __restrict__ X, const short* __restrict__ W,
              const float* __restrict__ bo, float* __restrict__ out)
{
  __shared__ __align__(16) short lds[24576];
  const int n = blockIdx.x;
  const int bxm = (n >> 3) & 15;
  const int byn = ((n & 7) << 1) | (n >> 7);
  const int tile_m = bxm * 128, tile_n = byn * 64;

  const int tid = threadIdx.x;
  const int wave = tid >> 6, lane = tid & 63;
  const int wr = wave >> 1, wc = wave & 1;
  const int q15 = lane & 15, q4 = lane >> 4;
  const int rl = lane >> 3;
  const int cswz = ((lane & 7) * 16) ^ (rl << 4);

  f32x4 acc[4][2];
#pragma unroll
  for (int i = 0; i < 4; ++i)
#pragma unroll
    for (int j = 0; j < 2; ++j) acc[i][j] = (f32x4){0.f, 0.f, 0.f, 0.f};

  auto stage = [&](int buf, int k0) {
    short* As = lds + buf * 12288;
    short* Bs = As + 8192;
#pragma unroll
    for (int s = 0; s < 6; ++s) {
      int idx = wave * 6 + s;
      if (idx < 16) {
        int row = idx * 8 + rl;
        GLDS(X + (size_t)(tile_m + row) * 1024 + k0 + (cswz >> 1), (char*)As + idx * 1024);
      } else {
        int i2 = idx - 16;
        int row = i2 * 8 + rl;
        GLDS(W + (size_t)(tile_n + row) * 1024 + k0 + (cswz >> 1), (char*)Bs + i2 * 1024);
      }
    }
  };

  stage(0, 0);
  __syncthreads();
  for (int t = 0; t < 16; ++t) {
    const int cur = t & 1;
    if (t < 15) stage(cur ^ 1, (t + 1) * 64);
    const short* As = lds + cur * 12288;
    const short* Bs = As + 8192;
#pragma unroll
    for (int kk = 0; kk < 2; ++kk) {
      const int kbyte = kk * 64 + q4 * 16;
      const int rswz = (q15 & 7) << 4;
      bf16x8 af[4], bfr[2];
#pragma unroll
      for (int i = 0; i < 4; ++i)
        af[i] = *(const bf16x8*)((const char*)As + (wr * 64 + i * 16 + q15) * 128 + (kbyte ^ rswz));
#pragma unroll
      for (int j = 0; j < 2; ++j)
        bfr[j] = *(const bf16x8*)((const char*)Bs + (wc * 32 + j * 16 + q15) * 128 + (kbyte ^ rswz));
#pragma unroll
      for (int i = 0; i < 4; ++i)
#pragma unroll
        for (int j = 0; j < 2; ++j)
          acc[i][j] = __builtin_amdgcn_mfma_f32_16x16x32_bf16(af[i], bfr[j], acc[i][j], 0, 0, 0);
    }
    __syncthreads();
  }

#pragma unroll
  for (int i = 0; i < 4; ++i)
#pragma unroll
    for (int j = 0; j < 2; ++j)
#pragma unroll
      for (int r = 0; r < 4; ++r) {
        int m = tile_m + wr * 64 + i * 16 + q4 * 4 + r;
        int nn = tile_n + wc * 32 + j * 16 + q15;
        out[(size_t)m * 1024 + nn] = acc[i][j][r] + bo[nn];
      }
}

// ---------------- fused rel-pos flash attention, swapped-operand form ----------------
// All MFMAs swapped: fragments hold S^T (s-rows, t-cols) so BD gathers, refill
// writes, P writes and O stores all become vector LDS/global ops.
__global__ __launch_bounds__(256, 4)
void attn_kernel(const short* __restrict__ qu, const short* __restrict__ qv,
                 const short* __restrict__ kmat, const short* __restrict__ vt,
                 const short* __restrict__ p,
                 float* __restrict__ Opart, float* __restrict__ larr)
{
  __shared__ __align__(16) short Ks[4096];   // [s_loc][dk], xor-swizzled
  __shared__ __align__(16) short Vs[4096];   // [dv][s_loc], xor-swizzled
  __shared__ __align__(16) short Bl[8192];   // per-wave 16 t-rows x 128 j-cols (circular), swizzled
  __shared__ __align__(16) short Pl[4096];   // per-wave 16 t-rows x 64 s-cols, swizzled

  // XCD swizzle: contiguous 128 blocks (one (b,sh) slice, 8 heads' K/V) per XCD
  const int nB = blockIdx.x;
  const int o = (nB & 7) * 128 + (nB >> 3);
  const int t0 = (o & 15) * 64;
  const int h = (o >> 4) & 15;
  const int z = o >> 8;
  const int b = z >> 1, sh = z & 1;

  const int tid = threadIdx.x;
  const int wave = tid >> 6, lane = tid & 63;
  const int q15 = lane & 15, q4 = lane >> 4;
  const size_t bh = (size_t)(b * 16 + h);
  const short* pW = p + (size_t)h * 65536;
  const int rswz = (q15 & 7) << 4;           // row swizzle (Ks/Vs/Bl/Pl rows keyed by q15)
  char* BlW = (char*)Bl + wave * 4096;
  char* PlW = (char*)Pl + wave * 2048;
  const int blrow = q15 * 256;               // Bl row base bytes
  const int plrow = q15 * 128;               // Pl row base bytes

  // staging geometry (reg-staged K/V)
  const int srow = tid >> 3;
  const int scol = (tid & 7) * 8;
  const int sdst = srow * 128 + ((scol * 2) ^ ((srow & 7) << 4));

  const int sbeg = sh * 512, send = sbeg + 512;
  const short* kg = kmat + (bh * 1024 + sbeg + srow) * 64 + scol;
  const short* vg = vt + (bh * 64 + srow) * 1024 + sbeg + scol;

  bf16x8 quf[2], qvf[2];
  {
    size_t base = (bh * 1024 + t0 + wave * 16 + q15) * 64 + q4 * 8;
    quf[0] = *(const bf16x8*)(qu + base);
    quf[1] = *(const bf16x8*)(qu + base + 32);
    qvf[0] = *(const bf16x8*)(qv + base);
    qvf[1] = *(const bf16x8*)(qv + base + 32);
  }
  bf16x8 ones;
#pragma unroll
  for (int i = 0; i < 8; ++i) ones[i] = (short)0x3F80;  // bf16 1.0

  f32x4 acco[4], accl;
#pragma unroll
  for (int g = 0; g < 4; ++g) acco[g] = (f32x4){0.f, 0.f, 0.f, 0.f};
  accl = (f32x4){0.f, 0.f, 0.f, 0.f};

  int live0 = -1, live1 = -1;

  // refill: Bwin[j][t] for j in [base, base+64); lane holds j = base+16g'+4q4+r at t=q15
  auto refill = [&](int base) {
    f32x4 bacc[4];
#pragma unroll
    for (int g = 0; g < 4; ++g) bacc[g] = (f32x4){0.f, 0.f, 0.f, 0.f};
#pragma unroll
    for (int kc = 0; kc < 2; ++kc) {
      const int kof = kc * 32 + q4 * 8;
#pragma unroll
      for (int g = 0; g < 4; ++g) {
        bf16x8 pf = *(const bf16x8*)(pW + (size_t)(base + g * 16 + q15) * 64 + kof);
        bacc[g] = __builtin_amdgcn_mfma_f32_16x16x32_bf16(pf, qvf[kc], bacc[g], 0, 0, 0);
      }
    }
    const int pbase = base & 127;
#pragma unroll
    for (int g = 0; g < 4; ++g) {
      unsigned a0 = __float_as_uint(bacc[g][0]); a0 = a0 + 0x7FFFu + ((a0 >> 16) & 1u);
      unsigned a1 = __float_as_uint(bacc[g][1]); a1 = a1 + 0x7FFFu + ((a1 >> 16) & 1u);
      unsigned a2 = __float_as_uint(bacc[g][2]); a2 = a2 + 0x7FFFu + ((a2 >> 16) & 1u);
      unsigned a3 = __float_as_uint(bacc[g][3]); a3 = a3 + 0x7FFFu + ((a3 >> 16) & 1u);
      u32x2 pk;
      pk[0] = (a0 >> 16) | (a1 & 0xFFFF0000u);
      pk[1] = (a2 >> 16) | (a3 & 0xFFFF0000u);
      int inrow = (pbase + 16 * g + 4 * q4) * 2;
      *(u32x2*)(BlW + blrow + (inrow ^ rswz)) = pk;
    }
  };

  // prologue: load tile 0 into regs
  bf16x8 kr0 = *(const bf16x8*)kg;
  bf16x8 kr1 = *(const bf16x8*)(kg + 2048);
  bf16x8 vr0 = *(const bf16x8*)vg;
  bf16x8 vr1 = *(const bf16x8*)(vg + 32768);

  for (int s0 = sbeg; s0 < send; s0 += 64) {
    __syncthreads();
    *(bf16x8*)((char*)Ks + sdst) = kr0;
    *(bf16x8*)((char*)Ks + sdst + 4096) = kr1;
    *(bf16x8*)((char*)Vs + sdst) = vr0;
    *(bf16x8*)((char*)Vs + sdst + 4096) = vr1;
    __syncthreads();
    if (s0 + 64 < send) {
      kg += 4096; vg += 64;
      kr0 = *(const bf16x8*)kg;
      kr1 = *(const bf16x8*)(kg + 2048);
      vr0 = *(const bf16x8*)vg;
      vr1 = *(const bf16x8*)(vg + 32768);
    }

    // AC^T = K . qu^T : accac[g][r] = S[t=q15-col][s = s0+16g+4q4+r]
    f32x4 accac[4];
#pragma unroll
    for (int g = 0; g < 4; ++g) accac[g] = (f32x4){0.f, 0.f, 0.f, 0.f};
    __builtin_amdgcn_s_setprio(1);
#pragma unroll
    for (int kc = 0; kc < 2; ++kc) {
      const int kbyte = kc * 64 + q4 * 16;
#pragma unroll
      for (int g = 0; g < 4; ++g) {
        bf16x8 kf = *(const bf16x8*)((const char*)Ks + (g * 16 + q15) * 128 + (kbyte ^ rswz));
        accac[g] = __builtin_amdgcn_mfma_f32_16x16x32_bf16(kf, quf[kc], accac[g], 0, 0, 0);
      }
    }
    __builtin_amdgcn_s_setprio(0);

    // BD circular-window maintenance (block-uniform)
    const int dist0 = (t0 > s0) ? (t0 - s0) : (s0 - t0);
    const int jbase = 960 - dist0;
    {
      int sl = (jbase >> 6) & 1;
      bool nd = sl ? (live1 != jbase) : (live0 != jbase);
      if (nd) { refill(jbase); if (sl) live1 = jbase; else live0 = jbase; }
      int b1 = jbase + 64;
      if (b1 <= 960) {
        int sl1 = sl ^ 1;
        bool nd1 = sl1 ? (live1 != b1) : (live0 != b1);
        if (nd1) { refill(b1); if (sl1) live1 = b1; else live0 = b1; }
      }
    }
    const int JB = jbase & 127;

    // scores + exp2 + pack P (bf16 truncation; l summed from same P via ones-MFMA)
    unsigned pk01[4], pk23[4];
    if (s0 != t0) {
      const bool below = (s0 < t0);
#pragma unroll
      for (int g = 0; g < 4; ++g) {
        int K = below ? (63 - 16 * wave - q15 + 16 * g + 4 * q4)
                      : (60 + 16 * wave + q15 - 16 * g - 4 * q4);
        int lo = JB + K;
        int par = lo & 1;
        int C = lo & ~1;
        unsigned w0 = *(const unsigned*)(BlW + blrow + (((((C + 0) & 127) * 2)) ^ rswz));
        unsigned w1 = *(const unsigned*)(BlW + blrow + (((((C + 2) & 127) * 2)) ^ rswz));
        unsigned w2 = *(const unsigned*)(BlW + blrow + (((((C + 4) & 127) * 2)) ^ rswz));
        unsigned u0 = par ? ((w1 << 16) | (w0 >> 16)) : w0;
        unsigned u1 = par ? ((w2 << 16) | (w1 >> 16)) : w1;
        float bd0, bd1, bd2, bd3;
        if (below) {
          bd0 = __uint_as_float(u0 << 16); bd1 = __uint_as_float(u0 & 0xFFFF0000u);
          bd2 = __uint_as_float(u1 << 16); bd3 = __uint_as_float(u1 & 0xFFFF0000u);
        } else {
          bd3 = __uint_as_float(u0 << 16); bd2 = __uint_as_float(u0 & 0xFFFF0000u);
          bd1 = __uint_as_float(u1 << 16); bd0 = __uint_as_float(u1 & 0xFFFF0000u);
        }
        float e0 = __builtin_amdgcn_exp2f(accac[g][0] + bd0);
        float e1 = __builtin_amdgcn_exp2f(accac[g][1] + bd1);
        float e2 = __builtin_amdgcn_exp2f(accac[g][2] + bd2);
        float e3 = __builtin_amdgcn_exp2f(accac[g][3] + bd3);
        pk01[g] = (__float_as_uint(e0) >> 16) | (__float_as_uint(e1) & 0xFFFF0000u);
        pk23[g] = (__float_as_uint(e2) >> 16) | (__float_as_uint(e3) & 0xFFFF0000u);
      }
    } else {
      // diagonal tile: JB==64, phys col = 127 - |t-s|
      const int tl = 16 * wave + q15;
#pragma unroll
      for (int g = 0; g < 4; ++g) {
        float ev[4];
#pragma unroll
        for (int r = 0; r < 4; ++r) {
          int e = tl - (16 * g + 4 * q4 + r);
          int d = e < 0 ? -e : e;
          unsigned hv = *(const unsigned short*)(BlW + blrow + ((((127 - d) * 2)) ^ rswz));
          float bd = __uint_as_float(hv << 16);
          ev[r] = __builtin_amdgcn_exp2f(accac[g][r] + bd);
        }
        pk01[g] = (__float_as_uint(ev[0]) >> 16) | (__float_as_uint(ev[1]) & 0xFFFF0000u);
        pk23[g] = (__float_as_uint(ev[2]) >> 16) | (__float_as_uint(ev[3]) & 0xFFFF0000u);
      }
    }

    // P -> Pl: lane's 16 values all in row t=q15, 4 runs of 4 consecutive s-cols
#pragma unroll
    for (int g = 0; g < 4; ++g) {
      u32x2 pk; pk[0] = pk01[g]; pk[1] = pk23[g];
      int inrow = (16 * g + 4 * q4) * 2;
      *(u32x2*)(PlW + plrow + (inrow ^ rswz)) = pk;
    }

    // O^T += V^T . P^T ; l += ones . P^T
    __builtin_amdgcn_s_setprio(1);
#pragma unroll
    for (int kc = 0; kc < 2; ++kc) {
      const int kbyte = kc * 64 + q4 * 16;
      bf16x8 pf = *(const bf16x8*)(PlW + plrow + (kbyte ^ rswz));
      accl = __builtin_amdgcn_mfma_f32_16x16x32_bf16(ones, pf, accl, 0, 0, 0);
#pragma unroll
      for (int g = 0; g < 4; ++g) {
        bf16x8 vf = *(const bf16x8*)((const char*)Vs + (g * 16 + q15) * 128 + (kbyte ^ rswz));
        acco[g] = __builtin_amdgcn_mfma_f32_16x16x32_bf16(vf, pf, acco[g], 0, 0, 0);
      }
    }
    __builtin_amdgcn_s_setprio(0);
  }

  // outputs: acco[g][r] = O^T[dv=16g+4q4+r][t=q15]  -> float4 stores
  size_t obase = ((size_t)(sh * 2 + b) * 16 + h) * 1024;
  const int tt = t0 + wave * 16 + q15;
#pragma unroll
  for (int g = 0; g < 4; ++g)
    *(f32x4*)(Opart + (obase + tt) * 64 + 16 * g + 4 * q4) = acco[g];
  if (lane < 16) larr[obase + tt] = accl[0];
}

// ---------------- combine split-s halves ----------------
__global__ void combine_k(const float* __restrict__ O, const float* __restrict__ larr,
                          short* __restrict__ x)
{
  int i = blockIdx.x * 256 + threadIdx.x;
  int dv4 = i & 15, rest = i >> 4;
  float4 a0 = *(const float4*)(O + (size_t)rest * 64 + dv4 * 4);
  float4 a1 = *(const float4*)(O + 2097152 + (size_t)rest * 64 + dv4 * 4);
  float l0 = larr[rest], l1 = larr[32768 + rest];
  float inv = 1.0f / (l0 + l1);
  int bq = rest >> 14, hq = (rest >> 10) & 15, tq = rest & 1023;
  short4v o;
  o[0] = f2b((a0.x + a1.x) * inv);
  o[1] = f2b((a0.y + a1.y) * inv);
  o[2] = f2b((a0.z + a1.z) * inv);
  o[3] = f2b((a0.w + a1.w) * inv);
  *(short4v*)(x + ((size_t)(bq * 1024 + tq) * 1024 + hq * 64 + dv4 * 4)) = o;
}

// ---------------- launch ----------------
extern "C" void kernel_launch(void* const* d_in, const int* in_sizes, int n_in,
                              void* d_out, int out_size, void* d_ws, size_t ws_size,
                              hipStream_t stream) {
  const float* query = (const float*)d_in[0];
  const float* key   = (const float*)d_in[1];
  const float* value = (const float*)d_in[2];
  const float* pos   = (const float*)d_in[3];
  const float* Wq = (const float*)d_in[4];  const float* bq = (const float*)d_in[5];
  const float* Wk = (const float*)d_in[6];  const float* bk = (const float*)d_in[7];
  const float* Wv = (const float*)d_in[8];  const float* bv = (const float*)d_in[9];
  const float* Wp = (const float*)d_in[10]; const float* bp = (const float*)d_in[11];
  const float* Wo = (const float*)d_in[12]; const float* bo = (const float*)d_in[13];
  const float* ub = (const float*)d_in[14]; const float* vb = (const float*)d_in[15];

  char* ws = (char*)d_ws;
  const size_t MB = 1 << 20;
  short* Wo_bf    = (short*)(ws);            // 2MB
  short* qu_bf    = (short*)(ws + 2 * MB);   // 4MB
  short* qv_bf    = (short*)(ws + 6 * MB);   // 4MB
  short* k_bf     = (short*)(ws + 10 * MB);  // 4MB
  short* vT_bf    = (short*)(ws + 14 * MB);  // 4MB
  short* p_bf     = (short*)(ws + 18 * MB);  // 2MB
  short* x_bf     = (short*)(ws + 20 * MB);  // 4MB
  short* query_bf = (short*)(ws + 24 * MB);  // 4MB  (dead after gemm_qkvp)
  short* key_bf   = (short*)(ws + 28 * MB);  // 4MB
  short* value_bf = (short*)(ws + 32 * MB);  // 4MB
  short* pos_bf   = (short*)(ws + 36 * MB);  // 2MB
  short* Wq_bf    = (short*)(ws + 38 * MB);  // 2MB
  short* Wk_bf    = (short*)(ws + 40 * MB);  // 2MB
  short* Wv_bf    = (short*)(ws + 42 * MB);  // 2MB
  short* Wp_bf    = (short*)(ws + 44 * MB);  // 2MB -> 46MB total
  // aliases (written after their underlying buffers are dead)
  float* Opart = (float*)(ws + 24 * MB);     // 16MB over query/key/value/pos
  float* larr  = (float*)(ws + 40 * MB);     // 256KB over Wk_bf

  CvtTab tab;
  tab.s[0] = query;           tab.d[0] = query_bf;
  tab.s[1] = query + 1048576; tab.d[1] = query_bf + 1048576;
  tab.s[2] = key;             tab.d[2] = key_bf;
  tab.s[3] = key + 1048576;   tab.d[3] = key_bf + 1048576;
  tab.s[4] = value;           tab.d[4] = value_bf;
  tab.s[5] = value + 1048576; tab.d[5] = value_bf + 1048576;
  tab.s[6] = pos;             tab.d[6] = pos_bf;
  tab.s[7] = Wq;              tab.d[7] = Wq_bf;
  tab.s[8] = Wk;              tab.d[8] = Wk_bf;
  tab.s[9] = Wv;              tab.d[9] = Wv_bf;
  tab.s[10] = Wp;             tab.d[10] = Wp_bf;
  tab.s[11] = Wo;             tab.d[11] = Wo_bf;
  hipLaunchKernelGGL(cvt_all, dim3(12288), dim3(256), 0, stream, tab);

  hipLaunchKernelGGL(gemm_qkvp, dim3(448), dim3(256), 0, stream,
                     query_bf, key_bf, value_bf, pos_bf,
                     Wq_bf, Wk_bf, Wv_bf, Wp_bf,
                     bq, bk, bv, bp, ub, vb,
                     qu_bf, qv_bf, k_bf, vT_bf, p_bf);

  hipLaunchKernelGGL(attn_kernel, dim3(1024), dim3(256), 0, stream,
                     qu_bf, qv_bf, k_bf, vT_bf, p_bf, Opart, larr);

  hipLaunchKernelGGL(combine_k, dim3(2048), dim3(256), 0, stream,
                     Opart, larr, x_bf);

  hipLaunchKernelGGL(gemm_out, dim3(256), dim3(256), 0, stream,
                     x_bf, Wo_bf, bo, (float*)d_out);
}